// Round 6
// baseline (4121.623 us; speedup 1.0000x reference)
//
#include <hip/hip_runtime.h>

typedef _Float16 half8 __attribute__((ext_vector_type(8)));
typedef _Float16 half4_t __attribute__((ext_vector_type(4)));
typedef _Float16 half2_t __attribute__((ext_vector_type(2)));
typedef float f32x4 __attribute__((ext_vector_type(4)));
typedef float f32x2 __attribute__((ext_vector_type(2)));
typedef unsigned long long u64;
typedef unsigned int u32;

#define SCALE 0.03125f   // 1/sqrt(1024)

// workspace layout (bytes)
#define XZ_OFF   0ULL            // f16 [8192][2048]  33,554,432
#define RING_OFF 33554432ULL     // ring: 16 groups x 8 slots x 67,584 B (xbf reused)
#define XBF_OFF  33554432ULL     // x f16 (pre-scan only; overlays ring)
#define WXZ_OFF  50331648ULL     // f16 [2048][1024]   4,194,304
#define WH_OFF   54525952ULL     // f16 [1024][1024]   2,097,152
#define WW_OFF   56623104ULL     // f16 [1024][1024]   2,097,152
#define VOTE_OFF 58720256ULL     // u32 [256][4] = 4096   (memset'd)
#define SEN_OFF  58724352ULL     // u32 [256][32] (128B stride) = 32768 (memset'd)

// ring slot internals: per (group, slot)
#define SLOTB 67584ULL
#define R_WVP 0        // f32 [16 slices][1024]  65,536
#define R_H   65536    // f16 [1024]              2,048

union Pk2 { u64 u[2]; half8 h8; };
union Pk1 { u64 u; half4_t h; };

// ---- transport helpers: uniform `mall` flag picks MALL vs same-XCD L2 (proven) ----
__device__ __forceinline__ float ldf(const float* p, bool mall) {
    return mall ? __hip_atomic_load(p, __ATOMIC_RELAXED, __HIP_MEMORY_SCOPE_AGENT) : *p;
}
__device__ __forceinline__ void stf(float* p, float v, bool mall) {
    if (mall) __hip_atomic_store(p, v, __ATOMIC_RELAXED, __HIP_MEMORY_SCOPE_AGENT); else *p = v;
}
__device__ __forceinline__ u64 ldq(const u64* p, bool mall) {
    return mall ? __hip_atomic_load(p, __ATOMIC_RELAXED, __HIP_MEMORY_SCOPE_AGENT) : *p;
}
__device__ __forceinline__ void stq(u64* p, u64 v, bool mall) {
    if (mall) __hip_atomic_store(p, v, __ATOMIC_RELAXED, __HIP_MEMORY_SCOPE_AGENT); else *p = v;
}
// sentinels: relaxed AGENT atomics (L1-bypassing, served at L2; r5 verified poll
// mechanism is not the bottleneck -- sync round-trip latency is structural)
__device__ __forceinline__ u32 ldsen(u32* p, bool mall) {
    return __hip_atomic_load(p, __ATOMIC_RELAXED, __HIP_MEMORY_SCOPE_AGENT);
}
__device__ __forceinline__ void stsen(u32* p, u32 v, bool mall) {
    __hip_atomic_store(p, v, __ATOMIC_RELAXED, __HIP_MEMORY_SCOPE_AGENT);
}
__device__ __forceinline__ f32x4 ld4f(const float* p, bool mall) {
    if (mall) { f32x4 v; v[0]=ldf(p,1); v[1]=ldf(p+1,1); v[2]=ldf(p+2,1); v[3]=ldf(p+3,1); return v; }
    return *(const f32x4*)p;
}
__device__ __forceinline__ void st4f(float* p, f32x4 v, bool mall) {
    if (mall) { stf(p,v[0],1); stf(p+1,v[1],1); stf(p+2,v[2],1); stf(p+3,v[3],1); }
    else *(f32x4*)p = v;
}

#define FDOT(a,b,acc) acc = __builtin_amdgcn_fdot2((a),(b),(acc),false)
__device__ __forceinline__ half2_t hp2(half8 v, int i) {
    half2_t r; r[0] = v[2*i]; r[1] = v[2*i+1]; return r;
}

__global__ void cvt_kernel(const float* __restrict__ in, _Float16* __restrict__ o, int n4) {
    int i = blockIdx.x * 256 + threadIdx.x;
    if (i < n4) {
        f32x4 v = ((const f32x4*)in)[i];
        half4_t h;
        h[0] = (_Float16)v[0]; h[1] = (_Float16)v[1];
        h[2] = (_Float16)v[2]; h[3] = (_Float16)v[3];
        ((half4_t*)o)[i] = h;
    }
}

// xz[m][n] = sum_k x[m][k] * Wxz[n][k];  M=8192, N=2048, K=1024  (unchanged, proven)
__launch_bounds__(256, 1)
__global__ void gemm_xz(const _Float16* __restrict__ A,
                        const _Float16* __restrict__ Bw,
                        _Float16* __restrict__ C) {
    __shared__ _Float16 As[128 * 40];
    __shared__ _Float16 Bs[128 * 40];
    const int tid = threadIdx.x;
    const int m0 = blockIdx.y * 128, n0 = blockIdx.x * 128;
    const int w = tid >> 6, lane = tid & 63;
    const int mw = (w >> 1) * 64, nw = (w & 1) * 64;
    const int row = lane & 15, q = lane >> 4;
    f32x4 acc[4][4];
    #pragma unroll
    for (int mt = 0; mt < 4; mt++)
        #pragma unroll
        for (int nt = 0; nt < 4; nt++)
            acc[mt][nt] = (f32x4){0.f, 0.f, 0.f, 0.f};

    for (int k0 = 0; k0 < 1024; k0 += 32) {
        __syncthreads();
        for (int cc = tid; cc < 512; cc += 256) {
            int r = cc >> 2, kc = (cc & 3) * 8;
            *(half8*)(&As[r * 40 + kc]) = *(const half8*)(&A[(size_t)(m0 + r) * 1024 + k0 + kc]);
            *(half8*)(&Bs[r * 40 + kc]) = *(const half8*)(&Bw[(size_t)(n0 + r) * 1024 + k0 + kc]);
        }
        __syncthreads();
        half8 af[4], bf[4];
        #pragma unroll
        for (int mt = 0; mt < 4; mt++) af[mt] = *(const half8*)(&As[(mw + mt * 16 + row) * 40 + q * 8]);
        #pragma unroll
        for (int nt = 0; nt < 4; nt++) bf[nt] = *(const half8*)(&Bs[(nw + nt * 16 + row) * 40 + q * 8]);
        #pragma unroll
        for (int mt = 0; mt < 4; mt++)
            #pragma unroll
            for (int nt = 0; nt < 4; nt++)
                acc[mt][nt] = __builtin_amdgcn_mfma_f32_16x16x32_f16(af[mt], bf[nt], acc[mt][nt], 0, 0, 0);
    }
    #pragma unroll
    for (int mt = 0; mt < 4; mt++)
        #pragma unroll
        for (int nt = 0; nt < 4; nt++)
            #pragma unroll
            for (int r = 0; r < 4; r++) {
                int gm = m0 + mw + mt * 16 + q * 4 + r;
                int gn = n0 + nw + nt * 16 + row;
                C[(size_t)gm * 2048 + gn] = (_Float16)acc[mt][nt][r];
            }
}

// Batch-partitioned persistent scan — SINGLE-SYNC fused edition.
// One sentinel per block per step (h + wvp published together).  Post-poll
// chain: {own-h u64 | full-h gather | 16x wv ld4f} -> fused 33-slot p_l round
// (0..15 wv.tape, 16..31 h.tape (q), 32 h.wv) -> B1 -> reduce (|| Wh matvec,
// av -> av_l) -> B2 -> write-softmax -> read-softmax via linearity -> rv on
// OWN dims (no rv_l round; slice cols == dims of threads s*16..s*16+15) ->
// epilogue -> B6 -> wvp fdot + h publish -> B7 -> sentinel.  4 barriers/step.
__launch_bounds__(256, 1)
__global__ void scan_kernel(const _Float16* __restrict__ xz,   // [8192][2048] f16
                            const float* __restrict__ tape_in, // [16][16][1024]
                            const float* __restrict__ h_in,    // [16][1024]
                            const float* __restrict__ bh,      // [1024]
                            const _Float16* __restrict__ wh,   // [1024][1024] f16
                            const _Float16* __restrict__ ww,   // [1024][1024] f16
                            char* ring,                        // 16 groups x 8 slots x SLOTB
                            u32* sen,                          // [256][32] (row 0 used)
                            u32* vote,                         // [256][4]
                            float* __restrict__ out) {
    const int bx = blockIdx.x;
    const int g = (bx & 7) * 2 + ((bx >> 3) & 1);   // batch group 0..15
    const int s = bx >> 4;                           // dim slice 0..15 (cols s*64..+63)
    const int tid = threadIdx.x;
    const int lane = tid & 63;
    const int grp = tid >> 4, c16 = tid & 15;        // reducer role
    const int cc = tid >> 2, q = tid & 3;            // matvec role: col cc, k-quarter q
    const bool isEpi = (grp == s);                   // owns output cols s*64+(c16*4)..+3
    const int ep4 = c16 * 4;                         // slice-local col base (epi threads)

    __shared__ __align__(16) _Float16 h_l[1024];     // full h_{t-1}, f16
    __shared__ __align__(16) _Float16 h_own[64];     // own slice of h_t
    __shared__ float av_l[64];                       // Wh matvec result (slice cols)
    __shared__ float p_l[256 * 35];                  // partials, stride 35 (slots 0..32)
    __shared__ float sc_l[33];                       // reduced scores
    __shared__ float pad_l[11000];                   // LDS > 80 KiB: force 1 block/CU
    __shared__ int sh_same;

    { volatile float* vp = pad_l; vp[tid] = 0.f; }   // keep pad alive

    // ---- per-group XCC vote (memset-initialized) ----
    if (tid == 0) {
        u32 xcc;
        asm volatile("s_getreg_b32 %0, hwreg(HW_REG_XCC_ID)" : "=s"(xcc));
        xcc &= 7u;
        __hip_atomic_store(&vote[bx * 4], xcc + 1u, __ATOMIC_RELAXED, __HIP_MEMORY_SCOPE_AGENT);
        int same = 1; u32 ref = 0;
        for (int m = 0; m < 16; m++) {
            int mb = m * 16 + ((g & 1) << 3) + (g >> 1);   // group member blockIdx
            u32 v; int spin = 0;
            while ((v = __hip_atomic_load(&vote[mb * 4], __ATOMIC_RELAXED, __HIP_MEMORY_SCOPE_AGENT)) == 0u) {
                if (++spin > 1000000) { v = 0xFFFFFFFFu; break; }
                __builtin_amdgcn_s_sleep(2);
            }
            if (m == 0) ref = v;
            if (v != ref || v == 0xFFFFFFFFu) same = 0;
        }
        sh_same = same;
    }
    __syncthreads();
    const bool mall = (sh_same == 0);
    bool dead = false;

    // ---- pinned weights ----
    const int qx = q << 1;
    half8 whr[32];   // Wh[col s*64+cc][k-quarter q], chunk order xor'd (bank-spread)
    {
        const _Float16* wp = wh + (size_t)(s * 64 + cc) * 1024 + q * 256;
        #pragma unroll
        for (int jj = 0; jj < 32; jj++)
            whr[jj] = *(const half8*)(wp + ((jj ^ qx) * 8));
    }
    half8 wwr[4][8]; // Ww rows 4*tid..+3, cols own 64 (row-slice for wvp partials)
    {
        const _Float16* wp = ww + (size_t)(tid * 4) * 1024 + s * 64;
        #pragma unroll
        for (int jj = 0; jj < 4; jj++)
            #pragma unroll
            for (int kk = 0; kk < 8; kk++)
                wwr[jj][kk] = *(const half8*)(wp + jj * 1024 + kk * 8);
    }
    // ---- replicated tape in registers: dims 4*tid..+3 for all 16 rows ----
    f32x4 tp[16];
    #pragma unroll
    for (int n = 0; n < 16; n++)
        tp[n] = *(const f32x4*)(&tape_in[(size_t)(g * 16 + n) * 1024 + tid * 4]);
    f32x4 bh4 = (f32x4){0.f, 0.f, 0.f, 0.f};
    if (isEpi) bh4 = *(const f32x4*)(&bh[s * 64 + ep4]);

    // ---- prologue: own h0 (f16) + full h0 into h_l ----
    half4_t own4;
    {
        f32x4 h4 = *(const f32x4*)(&h_in[(size_t)g * 1024 + tid * 4]);
        half4_t hh;
        hh[0] = (_Float16)h4[0]; hh[1] = (_Float16)h4[1];
        hh[2] = (_Float16)h4[2]; hh[3] = (_Float16)h4[3];
        own4 = hh;
        *(half4_t*)(&h_l[tid * 4]) = hh;
    }
    __syncthreads();

    u32* senrow = sen + (size_t)(g * 16 + s) * 32;
    const int senb = g * 16;

    float wan[16];
    f32x4 wv4 = (f32x4){0.f, 0.f, 0.f, 0.f};

    for (int t = 0; t <= 512; t++) {
        char* srd  = ring + (size_t)(g * 8 + ((t + 7) & 7)) * SLOTB;  // slot (t-1)&7
        char* spub = ring + (size_t)(g * 8 + (t & 7)) * SLOTB;        // slot t&7
        const bool havew = (t >= 1);
        // epilogue-thread xz prefetch (early; latency hides under poll)
        half4_t xp4h = (half4_t){(_Float16)0.f, (_Float16)0.f, (_Float16)0.f, (_Float16)0.f};
        half4_t zz4h = xp4h;
        if (isEpi && t < 512) {
            size_t m = (size_t)(g * 512 + t) * 2048 + s * 64 + ep4;
            xp4h = *(const half4_t*)(&xz[m]);
            zz4h = *(const half4_t*)(&xz[m + 1024]);
        }
        if (havew) {
            // ---- the single sync of the step ----
            if (!dead && lane < 16) {
                int spin = 0;
                while (ldsen(&sen[(size_t)(senb + lane) * 32], mall) < (u32)t) {
                    if (++spin > 2000000) { dead = true; break; }
                    __builtin_amdgcn_s_sleep(1);
                }
            }
            asm volatile("" ::: "memory");
            // own 4 dims of h_{t-1} (register, no LDS round-trip)
            { Pk1 u; u.u = ldq(&((const u64*)(srd + R_H))[tid], mall); own4 = u.h; }
            // gather full h_{t-1} -> h_l (for Wh matvec)
            if (tid < 128) {
                const u64* Hp = (const u64*)(srd + R_H);
                Pk2 u;
                u.u[0] = ldq(&Hp[tid * 2], mall);
                u.u[1] = ldq(&Hp[tid * 2 + 1], mall);
                *(half8*)(&h_l[tid * 8]) = u.h8;
            }
            // wv all-reduce: own 4 dims from 16 producer slices
            const float* Wp = (const float*)(srd + R_WVP);
            wv4 = (f32x4){0.f, 0.f, 0.f, 0.f};
            #pragma unroll
            for (int sl = 0; sl < 16; sl++)
                wv4 += ld4f(&Wp[sl * 1024 + tid * 4], mall);
        }
        // ---- fused 33-slot partials (tape still pre-write-(t-1)) ----
        {
            float h0 = (float)own4[0], h1 = (float)own4[1];
            float h2 = (float)own4[2], h3 = (float)own4[3];
            if (havew) {
                #pragma unroll
                for (int n = 0; n < 16; n++) {
                    f32x4 d = tp[n];
                    p_l[tid * 35 + n] = wv4[0]*d[0] + wv4[1]*d[1] + wv4[2]*d[2] + wv4[3]*d[3];
                }
                if (t < 512)
                    p_l[tid * 35 + 32] = h0*wv4[0] + h1*wv4[1] + h2*wv4[2] + h3*wv4[3];
            }
            if (t < 512) {
                #pragma unroll
                for (int n = 0; n < 16; n++) {
                    f32x4 d = tp[n];
                    p_l[tid * 35 + 16 + n] = h0*d[0] + h1*d[1] + h2*d[2] + h3*d[3];
                }
            }
        }
        __syncthreads();                                   // B1: p_l + h_l ready
        // ---- reduces (each (c16,grp) thread owns score grp and 16+grp) ----
        if (havew) {
            float sw = 0.f;
            #pragma unroll
            for (int m2 = 0; m2 < 16; m2++) sw += p_l[(c16 + 16 * m2) * 35 + grp];
            #pragma unroll
            for (int d2 = 1; d2 < 16; d2 <<= 1) sw += __shfl_xor(sw, d2, 16);
            if (c16 == 0) sc_l[grp] = sw;
            if (grp == 0 && t < 512) {
                float hw = 0.f;
                #pragma unroll
                for (int m2 = 0; m2 < 16; m2++) hw += p_l[(c16 + 16 * m2) * 35 + 32];
                #pragma unroll
                for (int d2 = 1; d2 < 16; d2 <<= 1) hw += __shfl_xor(hw, d2, 16);
                if (c16 == 0) sc_l[32] = hw;
            }
        }
        if (t < 512) {
            float sq = 0.f;
            #pragma unroll
            for (int m2 = 0; m2 < 16; m2++) sq += p_l[(c16 + 16 * m2) * 35 + 16 + grp];
            #pragma unroll
            for (int d2 = 1; d2 < 16; d2 <<= 1) sq += __shfl_xor(sq, d2, 16);
            if (c16 == 0) sc_l[16 + grp] = sq;
            // Wh matvec (overlaps reduce; h_l safe after B1) -> av_l (pre-B2)
            float a0 = 0.f, a1 = 0.f, a2 = 0.f, a3 = 0.f;
            #pragma unroll
            for (int jj = 0; jj < 32; jj++) {
                half8 hp8 = *(const half8*)(&h_l[q * 256 + ((jj ^ qx) * 8)]);
                half8 wc = whr[jj];
                FDOT(hp2(wc,0), hp2(hp8,0), a0);
                FDOT(hp2(wc,1), hp2(hp8,1), a1);
                FDOT(hp2(wc,2), hp2(hp8,2), a2);
                FDOT(hp2(wc,3), hp2(hp8,3), a3);
            }
            float av = (a0 + a1) + (a2 + a3);
            av += __shfl_xor(av, 1);
            av += __shfl_xor(av, 2);
            if (q == 0) av_l[cc] = av;
        }
        __syncthreads();                                   // B2: sc_l + av_l ready
        float hwv = 0.f;
        if (havew) {
            float e[16], mxw = -1e30f;
            #pragma unroll
            for (int n = 0; n < 16; n++) { e[n] = sc_l[n] * SCALE; mxw = fmaxf(mxw, e[n]); }
            float smw = 0.f;
            #pragma unroll
            for (int n = 0; n < 16; n++) { e[n] = __expf(e[n] - mxw); smw += e[n]; }
            float invw = 1.f / smw;
            #pragma unroll
            for (int n = 0; n < 16; n++) wan[n] = e[n] * invw;
            if (t < 512) hwv = sc_l[32];
        }
        if (t == 512) {   // finale: apply write of step 511, done
            #pragma unroll
            for (int n = 0; n < 16; n++) tp[n] += wan[n] * (wv4 - tp[n]);
            break;
        }
        // ---- read softmax via linearity + rv on OWN dims (all threads, parallel) ----
        float r[16], mx = -1e30f;
        if (havew) {
            #pragma unroll
            for (int n = 0; n < 16; n++) {
                r[n] = ((1.f - wan[n]) * sc_l[16 + n] + wan[n] * hwv) * SCALE;
                mx = fmaxf(mx, r[n]);
            }
        } else {
            #pragma unroll
            for (int n = 0; n < 16; n++) { r[n] = sc_l[16 + n] * SCALE; mx = fmaxf(mx, r[n]); }
        }
        float sm = 0.f;
        #pragma unroll
        for (int n = 0; n < 16; n++) { r[n] = __expf(r[n] - mx); sm += r[n]; }
        float inv = 1.f / sm;
        f32x4 rv4 = (f32x4){0.f, 0.f, 0.f, 0.f};
        if (havew) {
            float beta = 0.f;
            #pragma unroll
            for (int n = 0; n < 16; n++) {
                float ran = r[n] * inv;
                rv4 += (ran * (1.f - wan[n])) * tp[n];
                beta += ran * wan[n];
            }
            rv4 += beta * wv4;
        } else {
            #pragma unroll
            for (int n = 0; n < 16; n++) rv4 += (r[n] * inv) * tp[n];
        }
        // ---- epilogue: only the 16 threads whose dims are this slice's cols ----
        float o0 = 0.f, o1 = 0.f, o2 = 0.f, o3 = 0.f;
        if (isEpi) {
            f32x4 av4 = *(const f32x4*)(&av_l[ep4]);
            float hv0 = tanhf(av4[0] + (float)xp4h[0] + rv4[0] + bh4[0]);
            float hv1 = tanhf(av4[1] + (float)xp4h[1] + rv4[1] + bh4[1]);
            float hv2 = tanhf(av4[2] + (float)xp4h[2] + rv4[2] + bh4[2]);
            float hv3 = tanhf(av4[3] + (float)xp4h[3] + rv4[3] + bh4[3]);
            float g0 = (float)zz4h[0] + rv4[0] + hv0;
            float g1 = (float)zz4h[1] + rv4[1] + hv1;
            float g2 = (float)zz4h[2] + rv4[2] + hv2;
            float g3 = (float)zz4h[3] + rv4[3] + hv3;
            o0 = hv0 * g0 / (1.f + __expf(-g0));
            o1 = hv1 * g1 / (1.f + __expf(-g1));
            o2 = hv2 * g2 / (1.f + __expf(-g2));
            o3 = hv3 * g3 / (1.f + __expf(-g3));
            half4_t hh;
            hh[0] = (_Float16)hv0; hh[1] = (_Float16)hv1;
            hh[2] = (_Float16)hv2; hh[3] = (_Float16)hv3;
            *(half4_t*)(&h_own[ep4]) = hh;
        }
        // lazy tape update (write of step t-1) — AFTER rv used pre-write tape
        if (havew) {
            #pragma unroll
            for (int n = 0; n < 16; n++) tp[n] += wan[n] * (wv4 - tp[n]);
        }
        __syncthreads();                                   // B6: h_own ready
        // ---- wvp partials (all threads) + h publish, single drain ----
        half8 hr[8];
        #pragma unroll
        for (int kk = 0; kk < 8; kk++) hr[kk] = *(const half8*)(&h_own[kk * 8]);
        float w0 = 0.f, w1 = 0.f, w2 = 0.f, w3 = 0.f;
        #pragma unroll
        for (int kk = 0; kk < 8; kk++) {
            half8 h8 = hr[kk];
            #pragma unroll
            for (int pp = 0; pp < 4; pp++) {
                FDOT(hp2(wwr[0][kk],pp), hp2(h8,pp), w0);
                FDOT(hp2(wwr[1][kk],pp), hp2(h8,pp), w1);
                FDOT(hp2(wwr[2][kk],pp), hp2(h8,pp), w2);
                FDOT(hp2(wwr[3][kk],pp), hp2(h8,pp), w3);
            }
        }
        {
            f32x4 wq; wq[0] = w0; wq[1] = w1; wq[2] = w2; wq[3] = w3;
            st4f((float*)(spub + R_WVP) + s * 1024 + tid * 4, wq, mall);
        }
        if (tid < 8) {
            Pk2 u; u.h8 = *(const half8*)(&h_own[tid * 8]);
            u64* Hp = (u64*)(spub + R_H);
            stq(&Hp[s * 16 + tid * 2],     u.u[0], mall);
            stq(&Hp[s * 16 + tid * 2 + 1], u.u[1], mall);
        }
        __syncthreads();                                   // B7: vmcnt drain (h + wvp)
        if (tid == 0) stsen(&senrow[0], (u32)(t + 1), mall);
        // deferred out store (off the sentinel critical path)
        if (isEpi)
            *(f32x4*)(&out[(size_t)(g * 512 + t) * 1024 + s * 64 + ep4]) =
                (f32x4){o0, o1, o2, o3};
    }
    // ================= finale: write h_tape_final (slice 0 of each group) =================
    if (s == 0) {
        #pragma unroll
        for (int n = 0; n < 16; n++)
            *(f32x4*)(&out[8388608ULL + (size_t)(g * 16 + n) * 1024 + tid * 4]) = tp[n];
    }
}

extern "C" void kernel_launch(void* const* d_in, const int* in_sizes, int n_in,
                              void* d_out, int out_size, void* d_ws, size_t ws_size,
                              hipStream_t stream) {
    const float* x     = (const float*)d_in[0];
    const float* tape0 = (const float*)d_in[1];
    const float* h0    = (const float*)d_in[2];
    const float* Wh    = (const float*)d_in[3];
    const float* Wxz   = (const float*)d_in[4];
    const float* bh    = (const float*)d_in[5];
    const float* Ww    = (const float*)d_in[6];

    char* ws = (char*)d_ws;
    _Float16* xbf   = (_Float16*)(ws + XBF_OFF);
    _Float16* wxzbf = (_Float16*)(ws + WXZ_OFF);
    _Float16* whbf  = (_Float16*)(ws + WH_OFF);
    _Float16* wwbf  = (_Float16*)(ws + WW_OFF);
    _Float16* xzbf  = (_Float16*)(ws + XZ_OFF);
    char* ring      = ws + RING_OFF;
    u32* vote       = (u32*)(ws + VOTE_OFF);
    u32* sen        = (u32*)(ws + SEN_OFF);

    // vote (4 KB) + sentinels (32 KB): zeroed every launch
    hipMemsetAsync(ws + VOTE_OFF, 0, 4096 + 32768, stream);

    cvt_kernel<<<8192, 256, 0, stream>>>(x, xbf, 2097152);
    cvt_kernel<<<2048, 256, 0, stream>>>(Wxz, wxzbf, 524288);
    cvt_kernel<<<1024, 256, 0, stream>>>(Wh, whbf, 262144);
    cvt_kernel<<<1024, 256, 0, stream>>>(Ww, wwbf, 262144);

    gemm_xz<<<dim3(16, 64), 256, 0, stream>>>(xbf, wxzbf, xzbf);

    scan_kernel<<<256, 256, 0, stream>>>(xzbf, tape0, h0, bh, whbf, wwbf,
                                         ring, sen, vote, (float*)d_out);
}

// Round 8
// 3831.683 us; speedup vs baseline: 1.0757x; 1.0757x over previous
//
#include <hip/hip_runtime.h>

typedef _Float16 half8 __attribute__((ext_vector_type(8)));
typedef _Float16 half4_t __attribute__((ext_vector_type(4)));
typedef _Float16 half2_t __attribute__((ext_vector_type(2)));
typedef float f32x4 __attribute__((ext_vector_type(4)));
typedef float f32x2 __attribute__((ext_vector_type(2)));
typedef unsigned long long u64;
typedef unsigned int u32;

#define SCALE 0.03125f   // 1/sqrt(1024)

// workspace layout (bytes)
#define XZ_OFF   0ULL            // f16 [8192][2048]  33,554,432
#define RING_OFF 33554432ULL     // ring: 16 groups x 8 slots x 67,584 B (xbf reused)
#define XBF_OFF  33554432ULL     // x f16 (pre-scan only; overlays ring)
#define WXZ_OFF  50331648ULL     // f16 [2048][1024]   4,194,304
#define WH_OFF   54525952ULL     // f16 [1024][1024]   2,097,152
#define WW_OFF   56623104ULL     // f16 [1024][1024]   2,097,152
#define VOTE_OFF 58720256ULL     // u32 [256][4] = 4096   (memset'd)
#define SEN_OFF  58724352ULL     // u32 [256][32] (128B stride) = 32768 (memset'd)

// ring slot internals: per (group, slot)
#define SLOTB 67584ULL
#define R_WVP 0        // f32 [16 slices][1024]  65,536
#define R_H   65536    // f16 [1024]              2,048

union Pk2 { u64 u[2]; half8 h8; };
union Pk1 { u64 u; half4_t h; };

// ---- transport helpers: uniform `mall` flag picks MALL vs same-XCD L2 (proven) ----
__device__ __forceinline__ float ldf(const float* p, bool mall) {
    return mall ? __hip_atomic_load(p, __ATOMIC_RELAXED, __HIP_MEMORY_SCOPE_AGENT) : *p;
}
__device__ __forceinline__ void stf(float* p, float v, bool mall) {
    if (mall) __hip_atomic_store(p, v, __ATOMIC_RELAXED, __HIP_MEMORY_SCOPE_AGENT); else *p = v;
}
__device__ __forceinline__ u64 ldq(const u64* p, bool mall) {
    return mall ? __hip_atomic_load(p, __ATOMIC_RELAXED, __HIP_MEMORY_SCOPE_AGENT) : *p;
}
__device__ __forceinline__ void stq(u64* p, u64 v, bool mall) {
    if (mall) __hip_atomic_store(p, v, __ATOMIC_RELAXED, __HIP_MEMORY_SCOPE_AGENT); else *p = v;
}
// sentinels: relaxed AGENT atomics (L1-bypassing, served at L2; r5 A/B: poll
// mechanism is perf-neutral)
__device__ __forceinline__ u32 ldsen(u32* p, bool mall) {
    return __hip_atomic_load(p, __ATOMIC_RELAXED, __HIP_MEMORY_SCOPE_AGENT);
}
__device__ __forceinline__ void stsen(u32* p, u32 v, bool mall) {
    __hip_atomic_store(p, v, __ATOMIC_RELAXED, __HIP_MEMORY_SCOPE_AGENT);
}
__device__ __forceinline__ f32x4 ld4f(const float* p, bool mall) {
    if (mall) { f32x4 v; v[0]=ldf(p,1); v[1]=ldf(p+1,1); v[2]=ldf(p+2,1); v[3]=ldf(p+3,1); return v; }
    return *(const f32x4*)p;
}
__device__ __forceinline__ void st4f(float* p, f32x4 v, bool mall) {
    if (mall) { stf(p,v[0],1); stf(p+1,v[1],1); stf(p+2,v[2],1); stf(p+3,v[3],1); }
    else *(f32x4*)p = v;
}

#define FDOT(a,b,acc) acc = __builtin_amdgcn_fdot2((a),(b),(acc),false)
__device__ __forceinline__ half2_t hp2(half8 v, int i) {
    half2_t r; r[0] = v[2*i]; r[1] = v[2*i+1]; return r;
}

__global__ void cvt_kernel(const float* __restrict__ in, _Float16* __restrict__ o, int n4) {
    int i = blockIdx.x * 256 + threadIdx.x;
    if (i < n4) {
        f32x4 v = ((const f32x4*)in)[i];
        half4_t h;
        h[0] = (_Float16)v[0]; h[1] = (_Float16)v[1];
        h[2] = (_Float16)v[2]; h[3] = (_Float16)v[3];
        ((half4_t*)o)[i] = h;
    }
}

// xz[m][n] = sum_k x[m][k] * Wxz[n][k];  M=8192, N=2048, K=1024  (unchanged, proven)
__launch_bounds__(256, 1)
__global__ void gemm_xz(const _Float16* __restrict__ A,
                        const _Float16* __restrict__ Bw,
                        _Float16* __restrict__ C) {
    __shared__ _Float16 As[128 * 40];
    __shared__ _Float16 Bs[128 * 40];
    const int tid = threadIdx.x;
    const int m0 = blockIdx.y * 128, n0 = blockIdx.x * 128;
    const int w = tid >> 6, lane = tid & 63;
    const int mw = (w >> 1) * 64, nw = (w & 1) * 64;
    const int row = lane & 15, q = lane >> 4;
    f32x4 acc[4][4];
    #pragma unroll
    for (int mt = 0; mt < 4; mt++)
        #pragma unroll
        for (int nt = 0; nt < 4; nt++)
            acc[mt][nt] = (f32x4){0.f, 0.f, 0.f, 0.f};

    for (int k0 = 0; k0 < 1024; k0 += 32) {
        __syncthreads();
        for (int cc = tid; cc < 512; cc += 256) {
            int r = cc >> 2, kc = (cc & 3) * 8;
            *(half8*)(&As[r * 40 + kc]) = *(const half8*)(&A[(size_t)(m0 + r) * 1024 + k0 + kc]);
            *(half8*)(&Bs[r * 40 + kc]) = *(const half8*)(&Bw[(size_t)(n0 + r) * 1024 + k0 + kc]);
        }
        __syncthreads();
        half8 af[4], bf[4];
        #pragma unroll
        for (int mt = 0; mt < 4; mt++) af[mt] = *(const half8*)(&As[(mw + mt * 16 + row) * 40 + q * 8]);
        #pragma unroll
        for (int nt = 0; nt < 4; nt++) bf[nt] = *(const half8*)(&Bs[(nw + nt * 16 + row) * 40 + q * 8]);
        #pragma unroll
        for (int mt = 0; mt < 4; mt++)
            #pragma unroll
            for (int nt = 0; nt < 4; nt++)
                acc[mt][nt] = __builtin_amdgcn_mfma_f32_16x16x32_f16(af[mt], bf[nt], acc[mt][nt], 0, 0, 0);
    }
    #pragma unroll
    for (int mt = 0; mt < 4; mt++)
        #pragma unroll
        for (int nt = 0; nt < 4; nt++)
            #pragma unroll
            for (int r = 0; r < 4; r++) {
                int gm = m0 + mw + mt * 16 + q * 4 + r;
                int gn = n0 + nw + nt * 16 + row;
                C[(size_t)gm * 2048 + gn] = (_Float16)acc[mt][nt][r];
            }
}

// Batch-partitioned persistent scan — R2 structure + ONE fusion.
// R2 (proven 2898us) with the read-score round merged into the write-score
// round via linearity: rs_n = (1-wa_n) q_n + wa_n (h.wv), q_n = h.tape_old
// computed in the SAME 33-slot partials round.  Kills B3+B4+one reduce.
// Everything else R2-verbatim: spread 256-thread epilogue, rv_l round,
// matvec position, immediate tape update (wan/wv die within the iteration).
__launch_bounds__(256, 1)
__global__ void scan_kernel(const _Float16* __restrict__ xz,   // [8192][2048] f16
                            const float* __restrict__ tape_in, // [16][16][1024]
                            const float* __restrict__ h_in,    // [16][1024]
                            const float* __restrict__ bh,      // [1024]
                            const _Float16* __restrict__ wh,   // [1024][1024] f16
                            const _Float16* __restrict__ ww,   // [1024][1024] f16
                            char* ring,                        // 16 groups x 8 slots x SLOTB
                            u32* sen,                          // [256][32] (slot 0 used)
                            u32* vote,                         // [256][4]
                            float* __restrict__ out) {
    const int bx = blockIdx.x;
    const int g = (bx & 7) * 2 + ((bx >> 3) & 1);   // batch group 0..15
    const int s = bx >> 4;                           // dim slice 0..15 (cols s*64..+63)
    const int tid = threadIdx.x;
    const int lane = tid & 63;
    const int grp = tid >> 4, c16 = tid & 15;        // reducer role
    const int cc = tid >> 2, q = tid & 3;            // matvec/epilogue role

    __shared__ __align__(16) _Float16 h_l[1024];     // full h_{t-1}, f16
    __shared__ __align__(16) _Float16 h_own[64];     // own slice of h_t
    __shared__ __align__(16) float rv_l[1024];       // read_val (global dim order)
    __shared__ float p_l[256 * 35];                  // partials (slots 0..32), stride 35
    __shared__ float sc_l[33];                       // [0..15] wv.tape, [16..31] q, [32] h.wv
    __shared__ float pad_l[10200];                   // LDS > 80 KiB: force 1 block/CU
    __shared__ int sh_same;

    { volatile float* vp = pad_l; vp[tid] = 0.f; }   // keep pad alive

    // ---- per-group XCC vote (memset-initialized) ----
    if (tid == 0) {
        u32 xcc;
        asm volatile("s_getreg_b32 %0, hwreg(HW_REG_XCC_ID)" : "=s"(xcc));
        xcc &= 7u;
        __hip_atomic_store(&vote[bx * 4], xcc + 1u, __ATOMIC_RELAXED, __HIP_MEMORY_SCOPE_AGENT);
        int same = 1; u32 ref = 0;
        for (int m = 0; m < 16; m++) {
            int mb = m * 16 + ((g & 1) << 3) + (g >> 1);   // group member blockIdx
            u32 v; int spin = 0;
            while ((v = __hip_atomic_load(&vote[mb * 4], __ATOMIC_RELAXED, __HIP_MEMORY_SCOPE_AGENT)) == 0u) {
                if (++spin > 1000000) { v = 0xFFFFFFFFu; break; }
                __builtin_amdgcn_s_sleep(2);
            }
            if (m == 0) ref = v;
            if (v != ref || v == 0xFFFFFFFFu) same = 0;
        }
        sh_same = same;
    }
    __syncthreads();
    const bool mall = (sh_same == 0);
    bool dead = false;

    // ---- pinned weights ----
    const int qx = q << 1;
    half8 whr[32];   // Wh[col s*64+cc][k-quarter q], chunk order xor'd (bank-spread)
    {
        const _Float16* wp = wh + (size_t)(s * 64 + cc) * 1024 + q * 256;
        #pragma unroll
        for (int jj = 0; jj < 32; jj++)
            whr[jj] = *(const half8*)(wp + ((jj ^ qx) * 8));
    }
    half8 wwr[4][8]; // Ww rows 4*tid..+3, cols own 64 (row-slice for wvp partials)
    {
        const _Float16* wp = ww + (size_t)(tid * 4) * 1024 + s * 64;
        #pragma unroll
        for (int jj = 0; jj < 4; jj++)
            #pragma unroll
            for (int kk = 0; kk < 8; kk++)
                wwr[jj][kk] = *(const half8*)(wp + jj * 1024 + kk * 8);
    }
    // ---- replicated tape in registers: dims 4*tid..+3 for all 16 rows ----
    f32x4 tp[16];
    #pragma unroll
    for (int n = 0; n < 16; n++)
        tp[n] = *(const f32x4*)(&tape_in[(size_t)(g * 16 + n) * 1024 + tid * 4]);
    const float bhc = bh[s * 64 + cc];

    // ---- prologue: own h0 (f16 reg) + full h0 into h_l ----
    half4_t own4;
    {
        f32x4 h4 = *(const f32x4*)(&h_in[(size_t)g * 1024 + tid * 4]);
        half4_t hh;
        hh[0] = (_Float16)h4[0]; hh[1] = (_Float16)h4[1];
        hh[2] = (_Float16)h4[2]; hh[3] = (_Float16)h4[3];
        own4 = hh;
        *(half4_t*)(&h_l[tid * 4]) = hh;
    }
    __syncthreads();

    u32* senrow = sen + (size_t)(g * 16 + s) * 32;
    const int senb = g * 16;

    for (int t = 0; t <= 512; t++) {
        char* srd  = ring + (size_t)(g * 8 + ((t + 7) & 7)) * SLOTB;  // slot (t-1)&7
        char* spub = ring + (size_t)(g * 8 + (t & 7)) * SLOTB;        // slot t&7
        const bool havew = (t >= 1);
        // early x_proj / z prefetch (redundant over q; latency hides under poll)
        float xp = 0.f, zz = 0.f;
        if (t < 512) {
            size_t m = (size_t)(g * 512 + t) * 2048 + s * 64 + cc;
            xp = (float)xz[m];
            zz = (float)xz[m + 1024];
        }
        f32x4 wv4 = (f32x4){0.f, 0.f, 0.f, 0.f};
        if (havew) {
            // ---- the single sync of the step ----
            if (!dead && lane < 16) {
                int spin = 0;
                while (ldsen(&sen[(size_t)(senb + lane) * 32], mall) < (u32)t) {
                    if (++spin > 2000000) { dead = true; break; }
                    __builtin_amdgcn_s_sleep(1);
                }
            }
            asm volatile("" ::: "memory");
            // own 4 dims of h_{t-1} (direct 8B ring load; no LDS race)
            { Pk1 u; u.u = ldq(&((const u64*)(srd + R_H))[tid], mall); own4 = u.h; }
            // gather full h_{t-1} -> h_l (matvec operand; read post-B1)
            if (tid < 128) {
                const u64* Hp = (const u64*)(srd + R_H);
                Pk2 u;
                u.u[0] = ldq(&Hp[tid * 2], mall);
                u.u[1] = ldq(&Hp[tid * 2 + 1], mall);
                *(half8*)(&h_l[tid * 8]) = u.h8;
            }
            // wv all-reduce: own 4 dims from 16 producer slices
            const float* Wp = (const float*)(srd + R_WVP);
            #pragma unroll
            for (int sl = 0; sl < 16; sl++)
                wv4 += ld4f(&Wp[sl * 1024 + tid * 4], mall);
        }
        // ---- fused 33-slot partials (tape pre-write-(t-1)) ----
        {
            float h0 = (float)own4[0], h1 = (float)own4[1];
            float h2 = (float)own4[2], h3 = (float)own4[3];
            if (havew) {
                #pragma unroll
                for (int n = 0; n < 16; n++) {
                    f32x4 d = tp[n];
                    p_l[tid * 35 + n] = wv4[0]*d[0] + wv4[1]*d[1] + wv4[2]*d[2] + wv4[3]*d[3];
                }
                if (t < 512)
                    p_l[tid * 35 + 32] = h0*wv4[0] + h1*wv4[1] + h2*wv4[2] + h3*wv4[3];
            }
            if (t < 512) {
                #pragma unroll
                for (int n = 0; n < 16; n++) {
                    f32x4 d = tp[n];
                    p_l[tid * 35 + 16 + n] = h0*d[0] + h1*d[1] + h2*d[2] + h3*d[3];
                }
            }
        }
        __syncthreads();                                   // B1: p_l + h_l ready
        // ---- reduces: thread (c16,grp) owns slots grp and 16+grp; team grp==0 slot 32 ----
        if (havew) {
            float sw = 0.f;
            #pragma unroll
            for (int m2 = 0; m2 < 16; m2++) sw += p_l[(c16 + 16 * m2) * 35 + grp];
            #pragma unroll
            for (int d2 = 1; d2 < 16; d2 <<= 1) sw += __shfl_xor(sw, d2, 16);
            if (c16 == 0) sc_l[grp] = sw;
            if (grp == 0 && t < 512) {
                float hw = 0.f;
                #pragma unroll
                for (int m2 = 0; m2 < 16; m2++) hw += p_l[(c16 + 16 * m2) * 35 + 32];
                #pragma unroll
                for (int d2 = 1; d2 < 16; d2 <<= 1) hw += __shfl_xor(hw, d2, 16);
                if (c16 == 0) sc_l[32] = hw;
            }
        }
        if (t < 512) {
            float sq = 0.f;
            #pragma unroll
            for (int m2 = 0; m2 < 16; m2++) sq += p_l[(c16 + 16 * m2) * 35 + 16 + grp];
            #pragma unroll
            for (int d2 = 1; d2 < 16; d2 <<= 1) sq += __shfl_xor(sq, d2, 16);
            if (c16 == 0) sc_l[16 + grp] = sq;
        }
        __syncthreads();                                   // B2: sc_l ready
        float wan[16];
        if (havew) {   // write softmax (redundant per thread, R2 style)
            float e[16], mxw = -1e30f;
            #pragma unroll
            for (int n = 0; n < 16; n++) { e[n] = sc_l[n] * SCALE; mxw = fmaxf(mxw, e[n]); }
            float smw = 0.f;
            #pragma unroll
            for (int n = 0; n < 16; n++) { e[n] = __expf(e[n] - mxw); smw += e[n]; }
            float invw = 1.f / smw;
            #pragma unroll
            for (int n = 0; n < 16; n++) wan[n] = e[n] * invw;
        }
        if (t == 512) {   // finale: apply write of step 511, done
            #pragma unroll
            for (int n = 0; n < 16; n++) tp[n] += wan[n] * (wv4 - tp[n]);
            break;
        }
        // ---- read softmax via linearity (q from OLD tape) ----
        float r[16], mx = -1e30f;
        if (havew) {
            float hwv = sc_l[32];
            #pragma unroll
            for (int n = 0; n < 16; n++) {
                r[n] = ((1.f - wan[n]) * sc_l[16 + n] + wan[n] * hwv) * SCALE;
                mx = fmaxf(mx, r[n]);
            }
        } else {
            #pragma unroll
            for (int n = 0; n < 16; n++) { r[n] = sc_l[16 + n] * SCALE; mx = fmaxf(mx, r[n]); }
        }
        float sm = 0.f;
        #pragma unroll
        for (int n = 0; n < 16; n++) { r[n] = __expf(r[n] - mx); sm += r[n]; }
        float inv = 1.f / sm;
        // rv on own dims from OLD tape: rv = sum ra(1-wa) tp_old + (sum ra wa) wv
        f32x4 rv4 = (f32x4){0.f, 0.f, 0.f, 0.f};
        if (havew) {
            float beta = 0.f;
            #pragma unroll
            for (int n = 0; n < 16; n++) {
                float ran = r[n] * inv;
                rv4 += (ran * (1.f - wan[n])) * tp[n];
                beta += ran * wan[n];
            }
            rv4 += beta * wv4;
        } else {
            #pragma unroll
            for (int n = 0; n < 16; n++) rv4 += (r[n] * inv) * tp[n];
        }
        *(f32x4*)(&rv_l[tid * 4]) = rv4;
        // immediate tape update (write of step t-1) — rv used pre-update tape
        if (havew) {
            #pragma unroll
            for (int n = 0; n < 16; n++) tp[n] += wan[n] * (wv4 - tp[n]);
        }
        // Wh matvec (h_l stable since B1) — av lives in registers to epilogue
        float av;
        {
            float a0 = 0.f, a1 = 0.f, a2 = 0.f, a3 = 0.f;
            #pragma unroll
            for (int jj = 0; jj < 32; jj++) {
                half8 hp8 = *(const half8*)(&h_l[q * 256 + ((jj ^ qx) * 8)]);
                half8 wc = whr[jj];
                FDOT(hp2(wc,0), hp2(hp8,0), a0);
                FDOT(hp2(wc,1), hp2(hp8,1), a1);
                FDOT(hp2(wc,2), hp2(hp8,2), a2);
                FDOT(hp2(wc,3), hp2(hp8,3), a3);
            }
            av = (a0 + a1) + (a2 + a3);
            av += __shfl_xor(av, 1);
            av += __shfl_xor(av, 2);
        }
        __syncthreads();                                   // B5: rv_l ready
        // ---- epilogue (spread over 256 threads, q-redundant, R2 style) ----
        float rd = rv_l[s * 64 + cc];
        float hv = tanhf(av + xp + rd + bhc);
        float g2 = zz + rd + hv;
        float o = hv * g2 / (1.f + __expf(-g2));
        if (q == 0) h_own[cc] = (_Float16)hv;
        __syncthreads();                                   // B6: h_own ready
        // ---- wvp partials (all threads) + h publish, single drain ----
        half8 hr[8];
        #pragma unroll
        for (int kk = 0; kk < 8; kk++) hr[kk] = *(const half8*)(&h_own[kk * 8]);
        float w0 = 0.f, w1 = 0.f, w2 = 0.f, w3 = 0.f;
        #pragma unroll
        for (int kk = 0; kk < 8; kk++) {
            half8 h8 = hr[kk];
            #pragma unroll
            for (int pp = 0; pp < 4; pp++) {
                FDOT(hp2(wwr[0][kk],pp), hp2(h8,pp), w0);
                FDOT(hp2(wwr[1][kk],pp), hp2(h8,pp), w1);
                FDOT(hp2(wwr[2][kk],pp), hp2(h8,pp), w2);
                FDOT(hp2(wwr[3][kk],pp), hp2(h8,pp), w3);
            }
        }
        {
            f32x4 wq; wq[0] = w0; wq[1] = w1; wq[2] = w2; wq[3] = w3;
            st4f((float*)(spub + R_WVP) + s * 1024 + tid * 4, wq, mall);
        }
        if (tid < 8) {
            Pk2 u; u.h8 = *(const half8*)(&h_own[tid * 8]);
            u64* Hp = (u64*)(spub + R_H);
            stq(&Hp[s * 16 + tid * 2],     u.u[0], mall);
            stq(&Hp[s * 16 + tid * 2 + 1], u.u[1], mall);
        }
        __syncthreads();                                   // B7: vmcnt drain (h + wvp)
        if (tid == 0) stsen(&senrow[0], (u32)(t + 1), mall);
        // deferred out store (off the sentinel critical path)
        if (q == 0) out[(size_t)(g * 512 + t) * 1024 + s * 64 + cc] = o;
    }
    // ================= finale: write h_tape_final (slice 0 of each group) =================
    if (s == 0) {
        #pragma unroll
        for (int n = 0; n < 16; n++)
            *(f32x4*)(&out[8388608ULL + (size_t)(g * 16 + n) * 1024 + tid * 4]) = tp[n];
    }
}

extern "C" void kernel_launch(void* const* d_in, const int* in_sizes, int n_in,
                              void* d_out, int out_size, void* d_ws, size_t ws_size,
                              hipStream_t stream) {
    const float* x     = (const float*)d_in[0];
    const float* tape0 = (const float*)d_in[1];
    const float* h0    = (const float*)d_in[2];
    const float* Wh    = (const float*)d_in[3];
    const float* Wxz   = (const float*)d_in[4];
    const float* bh    = (const float*)d_in[5];
    const float* Ww    = (const float*)d_in[6];

    char* ws = (char*)d_ws;
    _Float16* xbf   = (_Float16*)(ws + XBF_OFF);
    _Float16* wxzbf = (_Float16*)(ws + WXZ_OFF);
    _Float16* whbf  = (_Float16*)(ws + WH_OFF);
    _Float16* wwbf  = (_Float16*)(ws + WW_OFF);
    _Float16* xzbf  = (_Float16*)(ws + XZ_OFF);
    char* ring      = ws + RING_OFF;
    u32* vote       = (u32*)(ws + VOTE_OFF);
    u32* sen        = (u32*)(ws + SEN_OFF);

    // vote (4 KB) + sentinels (32 KB): zeroed every launch
    hipMemsetAsync(ws + VOTE_OFF, 0, 4096 + 32768, stream);

    cvt_kernel<<<8192, 256, 0, stream>>>(x, xbf, 2097152);
    cvt_kernel<<<2048, 256, 0, stream>>>(Wxz, wxzbf, 524288);
    cvt_kernel<<<1024, 256, 0, stream>>>(Wh, whbf, 262144);
    cvt_kernel<<<1024, 256, 0, stream>>>(Ww, wwbf, 262144);

    gemm_xz<<<dim3(16, 64), 256, 0, stream>>>(xbf, wxzbf, xzbf);

    scan_kernel<<<256, 256, 0, stream>>>(xzbf, tape0, h0, bh, whbf, wwbf,
                                         ring, sen, vote, (float*)d_out);
}

// Round 9
// 3042.405 us; speedup vs baseline: 1.3547x; 1.2594x over previous
//
#include <hip/hip_runtime.h>

typedef _Float16 half8 __attribute__((ext_vector_type(8)));
typedef _Float16 half4_t __attribute__((ext_vector_type(4)));
typedef _Float16 half2_t __attribute__((ext_vector_type(2)));
typedef float f32x4 __attribute__((ext_vector_type(4)));
typedef float f32x2 __attribute__((ext_vector_type(2)));
typedef unsigned long long u64;
typedef unsigned int u32;

#define SCALE 0.03125f   // 1/sqrt(1024)

// workspace layout (bytes)
#define XZ_OFF   0ULL            // f16 [8192][2048]  33,554,432
#define RING_OFF 33554432ULL     // ring: 16 groups x 8 slots x 36,864 B (xbf reused)
#define XBF_OFF  33554432ULL     // x f16 (pre-scan only; overlays ring)
#define WXZ_OFF  50331648ULL     // f16 [2048][1024]   4,194,304
#define WH_OFF   54525952ULL     // f16 [1024][1024]   2,097,152
#define WW_OFF   56623104ULL     // f16 [1024][1024]   2,097,152
#define VOTE_OFF 58720256ULL     // u32 [256][4] = 4096   (memset'd)
#define SEN_OFF  58724352ULL     // u32 counters: cnt[g] at g*32 (128B stride) (memset'd)

// ring slot internals: per (group, slot)
#define SLOTB 36864ULL
#define R_WVP 0        // f16 [16 slices][1024]  32,768  (packed half4 per thread)
#define R_H   32768    // f16 [1024]              2,048

union Pk2 { u64 u[2]; half8 h8; };
union Pk1 { u64 u; half4_t h; };

// ---- transport helpers: uniform `mall` flag picks MALL vs same-XCD L2 (proven) ----
__device__ __forceinline__ u64 ldq(const u64* p, bool mall) {
    return mall ? __hip_atomic_load(p, __ATOMIC_RELAXED, __HIP_MEMORY_SCOPE_AGENT) : *p;
}
__device__ __forceinline__ void stq(u64* p, u64 v, bool mall) {
    if (mall) __hip_atomic_store(p, v, __ATOMIC_RELAXED, __HIP_MEMORY_SCOPE_AGENT); else *p = v;
}
// sentinel counter: relaxed AGENT load (L1-bypassing, served at L2; r5 A/B: poll
// mechanism perf-neutral). Producers atomicAdd(+1); 16 RMWs/step total -- no storm.
__device__ __forceinline__ u32 ldsen(u32* p) {
    return __hip_atomic_load(p, __ATOMIC_RELAXED, __HIP_MEMORY_SCOPE_AGENT);
}

#define FDOT(a,b,acc) acc = __builtin_amdgcn_fdot2((a),(b),(acc),false)
__device__ __forceinline__ half2_t hp2(half8 v, int i) {
    half2_t r; r[0] = v[2*i]; r[1] = v[2*i+1]; return r;
}

__global__ void cvt_kernel(const float* __restrict__ in, _Float16* __restrict__ o, int n4) {
    int i = blockIdx.x * 256 + threadIdx.x;
    if (i < n4) {
        f32x4 v = ((const f32x4*)in)[i];
        half4_t h;
        h[0] = (_Float16)v[0]; h[1] = (_Float16)v[1];
        h[2] = (_Float16)v[2]; h[3] = (_Float16)v[3];
        ((half4_t*)o)[i] = h;
    }
}

// xz[m][n] = sum_k x[m][k] * Wxz[n][k];  M=8192, N=2048, K=1024  (unchanged, proven)
__launch_bounds__(256, 1)
__global__ void gemm_xz(const _Float16* __restrict__ A,
                        const _Float16* __restrict__ Bw,
                        _Float16* __restrict__ C) {
    __shared__ _Float16 As[128 * 40];
    __shared__ _Float16 Bs[128 * 40];
    const int tid = threadIdx.x;
    const int m0 = blockIdx.y * 128, n0 = blockIdx.x * 128;
    const int w = tid >> 6, lane = tid & 63;
    const int mw = (w >> 1) * 64, nw = (w & 1) * 64;
    const int row = lane & 15, q = lane >> 4;
    f32x4 acc[4][4];
    #pragma unroll
    for (int mt = 0; mt < 4; mt++)
        #pragma unroll
        for (int nt = 0; nt < 4; nt++)
            acc[mt][nt] = (f32x4){0.f, 0.f, 0.f, 0.f};

    for (int k0 = 0; k0 < 1024; k0 += 32) {
        __syncthreads();
        for (int cc = tid; cc < 512; cc += 256) {
            int r = cc >> 2, kc = (cc & 3) * 8;
            *(half8*)(&As[r * 40 + kc]) = *(const half8*)(&A[(size_t)(m0 + r) * 1024 + k0 + kc]);
            *(half8*)(&Bs[r * 40 + kc]) = *(const half8*)(&Bw[(size_t)(n0 + r) * 1024 + k0 + kc]);
        }
        __syncthreads();
        half8 af[4], bf[4];
        #pragma unroll
        for (int mt = 0; mt < 4; mt++) af[mt] = *(const half8*)(&As[(mw + mt * 16 + row) * 40 + q * 8]);
        #pragma unroll
        for (int nt = 0; nt < 4; nt++) bf[nt] = *(const half8*)(&Bs[(nw + nt * 16 + row) * 40 + q * 8]);
        #pragma unroll
        for (int mt = 0; mt < 4; mt++)
            #pragma unroll
            for (int nt = 0; nt < 4; nt++)
                acc[mt][nt] = __builtin_amdgcn_mfma_f32_16x16x32_f16(af[mt], bf[nt], acc[mt][nt], 0, 0, 0);
    }
    #pragma unroll
    for (int mt = 0; mt < 4; mt++)
        #pragma unroll
        for (int nt = 0; nt < 4; nt++)
            #pragma unroll
            for (int r = 0; r < 4; r++) {
                int gm = m0 + mw + mt * 16 + q * 4 + r;
                int gn = n0 + nw + nt * 16 + row;
                C[(size_t)gm * 2048 + gn] = (_Float16)acc[mt][nt][r];
            }
}

// Batch-partitioned persistent scan — EXACT R2 structure (proven 2898us),
// transport-only changes: (1) wvp published as packed f16 half4 (8B/thread,
// halves the 64KB->32KB per-block gather; partials ~0.08 std, f16 ulp 6e-5,
// error ~1e-4 << absmax); (2) single accumulating group counter (1 poll load
// vs 16; producers atomicAdd(+1) after drain).  Register live ranges and all
// barriers identical to R2 (R6/R8 lesson: regalloc is the fragile resource).
__launch_bounds__(256, 1)
__global__ void scan_kernel(const _Float16* __restrict__ xz,   // [8192][2048] f16
                            const float* __restrict__ tape_in, // [16][16][1024]
                            const float* __restrict__ h_in,    // [16][1024]
                            const float* __restrict__ bh,      // [1024]
                            const _Float16* __restrict__ wh,   // [1024][1024] f16
                            const _Float16* __restrict__ ww,   // [1024][1024] f16
                            char* ring,                        // 16 groups x 8 slots x SLOTB
                            u32* sen,                          // cnt[g] at g*32
                            u32* vote,                         // [256][4]
                            float* __restrict__ out) {
    const int bx = blockIdx.x;
    const int g = (bx & 7) * 2 + ((bx >> 3) & 1);   // batch group 0..15
    const int s = bx >> 4;                           // dim slice 0..15 (cols s*64..+63)
    const int tid = threadIdx.x;
    const int lane = tid & 63;
    const int nn = tid >> 4, c16 = tid & 15;         // reducer role
    const int cc = tid >> 2, q = tid & 3;            // matvec/epilogue role

    __shared__ __align__(16) _Float16 h_prev[1024];  // full h_{t-1}, f16
    __shared__ __align__(16) _Float16 h_own[64];     // own slice of h_t
    __shared__ __align__(16) float rv_l[1024];       // read_val (global dim order)
    __shared__ float p_l[256 * 17];                  // score partials (pad 17)
    __shared__ float sc_l[16];
    __shared__ float pad_l[15000];                   // LDS > 80 KiB: force 1 block/CU
    __shared__ int sh_same;

    { volatile float* vp = pad_l; vp[tid] = 0.f; }   // keep pad alive

    // ---- per-group XCC vote (memset-initialized) ----
    if (tid == 0) {
        u32 xcc;
        asm volatile("s_getreg_b32 %0, hwreg(HW_REG_XCC_ID)" : "=s"(xcc));
        xcc &= 7u;
        __hip_atomic_store(&vote[bx * 4], xcc + 1u, __ATOMIC_RELAXED, __HIP_MEMORY_SCOPE_AGENT);
        int same = 1; u32 ref = 0;
        for (int m = 0; m < 16; m++) {
            int mb = m * 16 + ((g & 1) << 3) + (g >> 1);   // group member blockIdx
            u32 v; int spin = 0;
            while ((v = __hip_atomic_load(&vote[mb * 4], __ATOMIC_RELAXED, __HIP_MEMORY_SCOPE_AGENT)) == 0u) {
                if (++spin > 1000000) { v = 0xFFFFFFFFu; break; }
                __builtin_amdgcn_s_sleep(2);
            }
            if (m == 0) ref = v;
            if (v != ref || v == 0xFFFFFFFFu) same = 0;
        }
        sh_same = same;
    }
    __syncthreads();
    const bool mall = (sh_same == 0);
    bool dead = false;

    // ---- pinned weights ----
    const int qx = q << 1;
    half8 whr[32];   // Wh[col s*64+cc][k-quarter q], chunk order xor'd (bank-spread)
    {
        const _Float16* wp = wh + (size_t)(s * 64 + cc) * 1024 + q * 256;
        #pragma unroll
        for (int jj = 0; jj < 32; jj++)
            whr[jj] = *(const half8*)(wp + ((jj ^ qx) * 8));
    }
    half8 wwr[4][8]; // Ww rows 4*tid..+3, cols own 64 (row-slice for wvp partials)
    {
        const _Float16* wp = ww + (size_t)(tid * 4) * 1024 + s * 64;
        #pragma unroll
        for (int jj = 0; jj < 4; jj++)
            #pragma unroll
            for (int kk = 0; kk < 8; kk++)
                wwr[jj][kk] = *(const half8*)(wp + jj * 1024 + kk * 8);
    }
    // ---- replicated tape in registers: dims 4*tid..+3 for all 16 rows ----
    f32x4 tp[16];
    #pragma unroll
    for (int n = 0; n < 16; n++)
        tp[n] = *(const f32x4*)(&tape_in[(size_t)(g * 16 + n) * 1024 + tid * 4]);
    const float bhc = bh[s * 64 + cc];

    // ---- prologue: own h0 into h_prev ----
    {
        f32x4 h4 = *(const f32x4*)(&h_in[(size_t)g * 1024 + tid * 4]);
        half4_t hh;
        hh[0] = (_Float16)h4[0]; hh[1] = (_Float16)h4[1];
        hh[2] = (_Float16)h4[2]; hh[3] = (_Float16)h4[3];
        *(half4_t*)(&h_prev[tid * 4]) = hh;
    }
    __syncthreads();

    u32* cnt = sen + (size_t)g * 32;   // group counter (128B-strided)

    for (int t = 0; t <= 512; t++) {
        char* srd  = ring + (size_t)(g * 8 + ((t + 7) & 7)) * SLOTB;  // slot (t-1)&7
        char* spub = ring + (size_t)(g * 8 + (t & 7)) * SLOTB;        // slot t&7
        const bool havew = (t >= 1);
        // early x_proj / z prefetch (redundant over q; latency hides under poll)
        float xp = 0.f, zz = 0.f;
        if (t < 512) {
            size_t m = (size_t)(g * 512 + t) * 2048 + s * 64 + cc;
            xp = (float)xz[m];
            zz = (float)xz[m + 1024];
        }
        f32x4 wv4 = (f32x4){0.f, 0.f, 0.f, 0.f};
        if (havew) {
            // ---- the single sync of the step: one counter >= 16*t ----
            if (!dead && lane == 0) {
                int spin = 0;
                while (ldsen(cnt) < (u32)(16 * t)) {
                    if (++spin > 2000000) { dead = true; break; }
                    __builtin_amdgcn_s_sleep(1);
                }
            }
            asm volatile("" ::: "memory");
            // gather full h_{t-1} -> h_prev (read post-B1)
            if (tid < 128) {
                const u64* Hp = (const u64*)(srd + R_H);
                Pk2 u;
                u.u[0] = ldq(&Hp[tid * 2], mall);
                u.u[1] = ldq(&Hp[tid * 2 + 1], mall);
                *(half8*)(&h_prev[tid * 8]) = u.h8;
            }
            // wv all-reduce: own 4 dims from 16 producer slices (f16 packed, 8B each)
            const u64* Wp = (const u64*)(srd + R_WVP);
            #pragma unroll
            for (int sl = 0; sl < 16; sl++) {
                Pk1 u; u.u = ldq(&Wp[sl * 256 + tid], mall);
                wv4[0] += (float)u.h[0]; wv4[1] += (float)u.h[1];
                wv4[2] += (float)u.h[2]; wv4[3] += (float)u.h[3];
            }
            // write-score partials (wv . tape entering step t-1)
            {
                float p[16];
                #pragma unroll
                for (int n = 0; n < 16; n++) {
                    f32x4 d = tp[n];
                    p[n] = wv4[0]*d[0] + wv4[1]*d[1] + wv4[2]*d[2] + wv4[3]*d[3];
                }
                #pragma unroll
                for (int n = 0; n < 16; n++) p_l[tid * 17 + n] = p[n];
            }
            __syncthreads();                                   // B1: p_l + h_prev ready
            {
                float scw = 0.f;
                #pragma unroll
                for (int m2 = 0; m2 < 16; m2++) scw += p_l[(c16 + 16 * m2) * 17 + nn];
                #pragma unroll
                for (int d2 = 1; d2 < 16; d2 <<= 1) scw += __shfl_xor(scw, d2, 16);
                if (c16 == 0) sc_l[nn] = scw;
            }
            __syncthreads();                                   // B2: sc_l ready
            {   // write softmax (redundant per thread) + lazy tape update
                float e[16], mxw = -1e30f;
                #pragma unroll
                for (int n = 0; n < 16; n++) { e[n] = sc_l[n] * SCALE; mxw = fmaxf(mxw, e[n]); }
                float smw = 0.f;
                #pragma unroll
                for (int n = 0; n < 16; n++) { e[n] = __expf(e[n] - mxw); smw += e[n]; }
                float invw = 1.f / smw;
                #pragma unroll
                for (int n = 0; n < 16; n++) {
                    float wan = e[n] * invw;
                    f32x4 d = tp[n];
                    d[0] += wan * (wv4[0] - d[0]);
                    d[1] += wan * (wv4[1] - d[1]);
                    d[2] += wan * (wv4[2] - d[2]);
                    d[3] += wan * (wv4[3] - d[3]);
                    tp[n] = d;
                }
            }
        }
        if (t == 512) break;   // finale: tape has write of step 511 applied

        // read-score partials (h_{t-1} . tape entering step t)
        {
            half4_t hh = *(const half4_t*)(&h_prev[tid * 4]);
            float h0 = (float)hh[0], h1 = (float)hh[1], h2 = (float)hh[2], h3 = (float)hh[3];
            float p[16];
            #pragma unroll
            for (int n = 0; n < 16; n++) {
                f32x4 d = tp[n];
                p[n] = h0*d[0] + h1*d[1] + h2*d[2] + h3*d[3];
            }
            #pragma unroll
            for (int n = 0; n < 16; n++) p_l[tid * 17 + n] = p[n];
        }
        __syncthreads();                                       // B3
        float sc = 0.f;
        #pragma unroll
        for (int m2 = 0; m2 < 16; m2++) sc += p_l[(c16 + 16 * m2) * 17 + nn];
        #pragma unroll
        for (int d2 = 1; d2 < 16; d2 <<= 1) sc += __shfl_xor(sc, d2, 16);
        if (c16 == 0) sc_l[nn] = sc;
        __syncthreads();                                       // B4
        float r[16], mx = -1e30f;
        #pragma unroll
        for (int n = 0; n < 16; n++) { r[n] = sc_l[n] * SCALE; mx = fmaxf(mx, r[n]); }
        float sm = 0.f;
        #pragma unroll
        for (int n = 0; n < 16; n++) { r[n] = __expf(r[n] - mx); sm += r[n]; }
        float inv = 1.f / sm;
        // read_val, own 4 dims (from register tape)
        f32x4 rv4 = (f32x4){0.f, 0.f, 0.f, 0.f};
        #pragma unroll
        for (int n = 0; n < 16; n++) rv4 += (r[n] * inv) * tp[n];
        *(f32x4*)(&rv_l[tid * 4]) = rv4;
        // Wh matvec (col-role): full h_{t-1} from LDS, xor'd chunk order
        float a0 = 0.f, a1 = 0.f, a2 = 0.f, a3 = 0.f;
        #pragma unroll
        for (int jj = 0; jj < 32; jj++) {
            half8 hp8 = *(const half8*)(&h_prev[q * 256 + ((jj ^ qx) * 8)]);
            half8 wc = whr[jj];
            FDOT(hp2(wc,0), hp2(hp8,0), a0);
            FDOT(hp2(wc,1), hp2(hp8,1), a1);
            FDOT(hp2(wc,2), hp2(hp8,2), a2);
            FDOT(hp2(wc,3), hp2(hp8,3), a3);
        }
        float av = (a0 + a1) + (a2 + a3);
        av += __shfl_xor(av, 1);
        av += __shfl_xor(av, 2);
        __syncthreads();                                       // B5: rv_l ready
        float rd = rv_l[s * 64 + cc];
        float hv = tanhf(av + xp + rd + bhc);
        float g2 = zz + rd + hv;
        float o = hv * g2 / (1.f + __expf(-g2));
        if (q == 0) h_own[cc] = (_Float16)hv;
        __syncthreads();                                       // B6: h_own ready
        // wvp partials: rows 4*tid..+3 over own 64 k (h_own broadcast reads)
        half8 hr[8];
        #pragma unroll
        for (int kk = 0; kk < 8; kk++) hr[kk] = *(const half8*)(&h_own[kk * 8]);
        float w0 = 0.f, w1 = 0.f, w2 = 0.f, w3 = 0.f;
        #pragma unroll
        for (int kk = 0; kk < 8; kk++) {
            half8 h8 = hr[kk];
            #pragma unroll
            for (int pp = 0; pp < 4; pp++) {
                FDOT(hp2(wwr[0][kk],pp), hp2(h8,pp), w0);
                FDOT(hp2(wwr[1][kk],pp), hp2(h8,pp), w1);
                FDOT(hp2(wwr[2][kk],pp), hp2(h8,pp), w2);
                FDOT(hp2(wwr[3][kk],pp), hp2(h8,pp), w3);
            }
        }
        {   // publish wvp (packed f16 half4, 8B) + h slice into slot t&7
            Pk1 wq;
            wq.h = (half4_t){(_Float16)w0, (_Float16)w1, (_Float16)w2, (_Float16)w3};
            stq(&((u64*)(spub + R_WVP))[s * 256 + tid], wq.u, mall);
            if (tid < 8) {
                Pk2 u; u.h8 = *(const half8*)(&h_own[tid * 8]);
                u64* Hp = (u64*)(spub + R_H);
                stq(&Hp[s * 16 + tid * 2],     u.u[0], mall);
                stq(&Hp[s * 16 + tid * 2 + 1], u.u[1], mall);
            }
        }
        __syncthreads();                                       // B7: vmcnt drain (h + wvp)
        if (tid == 0)
            __hip_atomic_fetch_add(cnt, 1u, __ATOMIC_RELAXED, __HIP_MEMORY_SCOPE_AGENT);
        // deferred out store (off the sentinel critical path)
        if (q == 0) out[(size_t)(g * 512 + t) * 1024 + s * 64 + cc] = o;
    }
    // ================= finale: write h_tape_final (slice 0 of each group) =================
    if (s == 0) {
        #pragma unroll
        for (int n = 0; n < 16; n++)
            *(f32x4*)(&out[8388608ULL + (size_t)(g * 16 + n) * 1024 + tid * 4]) = tp[n];
    }
}

extern "C" void kernel_launch(void* const* d_in, const int* in_sizes, int n_in,
                              void* d_out, int out_size, void* d_ws, size_t ws_size,
                              hipStream_t stream) {
    const float* x     = (const float*)d_in[0];
    const float* tape0 = (const float*)d_in[1];
    const float* h0    = (const float*)d_in[2];
    const float* Wh    = (const float*)d_in[3];
    const float* Wxz   = (const float*)d_in[4];
    const float* bh    = (const float*)d_in[5];
    const float* Ww    = (const float*)d_in[6];

    char* ws = (char*)d_ws;
    _Float16* xbf   = (_Float16*)(ws + XBF_OFF);
    _Float16* wxzbf = (_Float16*)(ws + WXZ_OFF);
    _Float16* whbf  = (_Float16*)(ws + WH_OFF);
    _Float16* wwbf  = (_Float16*)(ws + WW_OFF);
    _Float16* xzbf  = (_Float16*)(ws + XZ_OFF);
    char* ring      = ws + RING_OFF;
    u32* vote       = (u32*)(ws + VOTE_OFF);
    u32* sen        = (u32*)(ws + SEN_OFF);

    // vote (4 KB) + counters (2 KB region): zeroed every launch
    hipMemsetAsync(ws + VOTE_OFF, 0, 4096 + 32768, stream);

    cvt_kernel<<<8192, 256, 0, stream>>>(x, xbf, 2097152);
    cvt_kernel<<<2048, 256, 0, stream>>>(Wxz, wxzbf, 524288);
    cvt_kernel<<<1024, 256, 0, stream>>>(Wh, whbf, 262144);
    cvt_kernel<<<1024, 256, 0, stream>>>(Ww, wwbf, 262144);

    gemm_xz<<<dim3(16, 64), 256, 0, stream>>>(xbf, wxzbf, xzbf);

    scan_kernel<<<256, 256, 0, stream>>>(xzbf, tape0, h0, bh, whbf, wwbf,
                                         ring, sen, vote, (float*)d_out);
}

// Round 10
// 2702.705 us; speedup vs baseline: 1.5250x; 1.1257x over previous
//
#include <hip/hip_runtime.h>

typedef _Float16 half8 __attribute__((ext_vector_type(8)));
typedef _Float16 half4_t __attribute__((ext_vector_type(4)));
typedef _Float16 half2_t __attribute__((ext_vector_type(2)));
typedef float f32x4 __attribute__((ext_vector_type(4)));
typedef float f32x2 __attribute__((ext_vector_type(2)));
typedef unsigned long long u64;
typedef unsigned int u32;

#define SCALE 0.03125f   // 1/sqrt(1024)

// workspace layout (bytes)
#define XZ_OFF   0ULL            // f16 [8192][2048]  33,554,432
#define RING_OFF 33554432ULL     // ring: 16 groups x 8 slots x 36,864 B (xbf reused)
#define XBF_OFF  33554432ULL     // x f16 (pre-scan only; overlays ring)
#define WXZ_OFF  50331648ULL     // f16 [2048][1024]   4,194,304
#define WH_OFF   54525952ULL     // f16 [1024][1024]   2,097,152
#define WW_OFF   56623104ULL     // f16 [1024][1024]   2,097,152
#define VOTE_OFF 58720256ULL     // u32 [256][4] = 4096   (memset'd)
#define SEN_OFF  58724352ULL     // u32 [256][32] (128B stride) = 32768 (memset'd)

// ring slot internals: per (group, slot)
#define SLOTB 36864ULL
#define R_WVP 0        // f16 [16 slices][1024]  32,768  (packed half2 per thread)
#define R_H   32768    // f16 [1024]              2,048

union Pk2 { u64 u[2]; half8 h8; };
union PkW { u32 u; half2_t h; };

// ---- transport helpers: uniform `mall` flag picks MALL vs same-XCD L2 (proven) ----
__device__ __forceinline__ u64 ldq(const u64* p, bool mall) {
    return mall ? __hip_atomic_load(p, __ATOMIC_RELAXED, __HIP_MEMORY_SCOPE_AGENT) : *p;
}
__device__ __forceinline__ void stq(u64* p, u64 v, bool mall) {
    if (mall) __hip_atomic_store(p, v, __ATOMIC_RELAXED, __HIP_MEMORY_SCOPE_AGENT); else *p = v;
}
__device__ __forceinline__ u32 ldw(const u32* p, bool mall) {
    return mall ? __hip_atomic_load(p, __ATOMIC_RELAXED, __HIP_MEMORY_SCOPE_AGENT) : *p;
}
__device__ __forceinline__ void stw(u32* p, u32 v, bool mall) {
    if (mall) __hip_atomic_store(p, v, __ATOMIC_RELAXED, __HIP_MEMORY_SCOPE_AGENT); else *p = v;
}
// sentinels: relaxed AGENT atomics on 16 INDEPENDENT 128B-strided lines
// (R2 mechanism — parallel-line poll; R9's single accumulating counter
// serialized 16 RMWs on one TCC line and cost ~+145us)
__device__ __forceinline__ u32 ldsen(u32* p) {
    return __hip_atomic_load(p, __ATOMIC_RELAXED, __HIP_MEMORY_SCOPE_AGENT);
}
__device__ __forceinline__ void stsen(u32* p, u32 v) {
    __hip_atomic_store(p, v, __ATOMIC_RELAXED, __HIP_MEMORY_SCOPE_AGENT);
}

#define FDOT(a,b,acc) acc = __builtin_amdgcn_fdot2((a),(b),(acc),false)
__device__ __forceinline__ half2_t hp2(half8 v, int i) {
    half2_t r; r[0] = v[2*i]; r[1] = v[2*i+1]; return r;
}

__global__ void cvt_kernel(const float* __restrict__ in, _Float16* __restrict__ o, int n4) {
    int i = blockIdx.x * 256 + threadIdx.x;
    if (i < n4) {
        f32x4 v = ((const f32x4*)in)[i];
        half4_t h;
        h[0] = (_Float16)v[0]; h[1] = (_Float16)v[1];
        h[2] = (_Float16)v[2]; h[3] = (_Float16)v[3];
        ((half4_t*)o)[i] = h;
    }
}

// xz[m][n] = sum_k x[m][k] * Wxz[n][k];  M=8192, N=2048, K=1024  (unchanged, proven)
__launch_bounds__(256, 1)
__global__ void gemm_xz(const _Float16* __restrict__ A,
                        const _Float16* __restrict__ Bw,
                        _Float16* __restrict__ C) {
    __shared__ _Float16 As[128 * 40];
    __shared__ _Float16 Bs[128 * 40];
    const int tid = threadIdx.x;
    const int m0 = blockIdx.y * 128, n0 = blockIdx.x * 128;
    const int w = tid >> 6, lane = tid & 63;
    const int mw = (w >> 1) * 64, nw = (w & 1) * 64;
    const int row = lane & 15, q = lane >> 4;
    f32x4 acc[4][4];
    #pragma unroll
    for (int mt = 0; mt < 4; mt++)
        #pragma unroll
        for (int nt = 0; nt < 4; nt++)
            acc[mt][nt] = (f32x4){0.f, 0.f, 0.f, 0.f};

    for (int k0 = 0; k0 < 1024; k0 += 32) {
        __syncthreads();
        for (int cc = tid; cc < 512; cc += 256) {
            int r = cc >> 2, kc = (cc & 3) * 8;
            *(half8*)(&As[r * 40 + kc]) = *(const half8*)(&A[(size_t)(m0 + r) * 1024 + k0 + kc]);
            *(half8*)(&Bs[r * 40 + kc]) = *(const half8*)(&Bw[(size_t)(n0 + r) * 1024 + k0 + kc]);
        }
        __syncthreads();
        half8 af[4], bf[4];
        #pragma unroll
        for (int mt = 0; mt < 4; mt++) af[mt] = *(const half8*)(&As[(mw + mt * 16 + row) * 40 + q * 8]);
        #pragma unroll
        for (int nt = 0; nt < 4; nt++) bf[nt] = *(const half8*)(&Bs[(nw + nt * 16 + row) * 40 + q * 8]);
        #pragma unroll
        for (int mt = 0; mt < 4; mt++)
            #pragma unroll
            for (int nt = 0; nt < 4; nt++)
                acc[mt][nt] = __builtin_amdgcn_mfma_f32_16x16x32_f16(af[mt], bf[nt], acc[mt][nt], 0, 0, 0);
    }
    #pragma unroll
    for (int mt = 0; mt < 4; mt++)
        #pragma unroll
        for (int nt = 0; nt < 4; nt++)
            #pragma unroll
            for (int r = 0; r < 4; r++) {
                int gm = m0 + mw + mt * 16 + q * 4 + r;
                int gn = n0 + nw + nt * 16 + row;
                C[(size_t)gm * 2048 + gn] = (_Float16)acc[mt][nt][r];
            }
}

// Batch-partitioned persistent scan — R2 dataflow, 512-THREAD geometry.
// Per-thread ownership halved (2 dims): pinned arrays = whr 64 + wwr 64 +
// tp 32 = 160 VGPRs -> genuinely fit (R2's 320-VGPR demand forced hidden
// per-step weight reloads from L1/L2).  2 waves/SIMD -> LDS/L2 latency of
// one wave hides under the other's VALU.  Transport: f16 wvp (R9, proven)
// + 16 independent 128B-strided sentinels polled with relaxed loads (R2).
__launch_bounds__(512, 1)
__global__ void scan_kernel(const _Float16* __restrict__ xz,   // [8192][2048] f16
                            const float* __restrict__ tape_in, // [16][16][1024]
                            const float* __restrict__ h_in,    // [16][1024]
                            const float* __restrict__ bh,      // [1024]
                            const _Float16* __restrict__ wh,   // [1024][1024] f16
                            const _Float16* __restrict__ ww,   // [1024][1024] f16
                            char* ring,                        // 16 groups x 8 slots x SLOTB
                            u32* sen,                          // [256][32]
                            u32* vote,                         // [256][4]
                            float* __restrict__ out) {
    const int bx = blockIdx.x;
    const int g = (bx & 7) * 2 + ((bx >> 3) & 1);   // batch group 0..15
    const int s = bx >> 4;                           // dim slice 0..15 (cols s*64..+63)
    const int tid = threadIdx.x;                     // 0..511
    const int lane = tid & 63;
    const int cc = tid >> 3, q = tid & 7;            // col-role: col cc (0..63), k-eighth q
    const int nn = tid >> 5, c32 = tid & 31;         // reducer role (16 rows x 32 threads)

    __shared__ __align__(16) _Float16 h_prev[1024];  // full h_{t-1}, f16
    __shared__ __align__(16) _Float16 h_own[64];     // own slice of h_t
    __shared__ __align__(16) float rv_l[1024];       // read_val (global dim order)
    __shared__ float p_l[512 * 17];                  // score partials (pad 17)
    __shared__ float sc_l[16];
    __shared__ float pad_l[10000];                   // LDS > 80 KiB: force 1 block/CU
    __shared__ int sh_same;

    { volatile float* vp = pad_l; vp[tid] = 0.f; }   // keep pad alive

    // ---- per-group XCC vote (memset-initialized) ----
    if (tid == 0) {
        u32 xcc;
        asm volatile("s_getreg_b32 %0, hwreg(HW_REG_XCC_ID)" : "=s"(xcc));
        xcc &= 7u;
        __hip_atomic_store(&vote[bx * 4], xcc + 1u, __ATOMIC_RELAXED, __HIP_MEMORY_SCOPE_AGENT);
        int same = 1; u32 ref = 0;
        for (int m = 0; m < 16; m++) {
            int mb = m * 16 + ((g & 1) << 3) + (g >> 1);   // group member blockIdx
            u32 v; int spin = 0;
            while ((v = __hip_atomic_load(&vote[mb * 4], __ATOMIC_RELAXED, __HIP_MEMORY_SCOPE_AGENT)) == 0u) {
                if (++spin > 1000000) { v = 0xFFFFFFFFu; break; }
                __builtin_amdgcn_s_sleep(2);
            }
            if (m == 0) ref = v;
            if (v != ref || v == 0xFFFFFFFFu) same = 0;
        }
        sh_same = same;
    }
    __syncthreads();
    const bool mall = (sh_same == 0);
    bool dead = false;

    // ---- pinned weights (fit in VGPRs at 512-thread split) ----
    const int qx = q << 1;
    half8 whr[16];   // Wh[col s*64+cc][k-eighth q], chunk order xor'd (bank-spread)
    {
        const _Float16* wp = wh + (size_t)(s * 64 + cc) * 1024 + q * 128;
        #pragma unroll
        for (int jj = 0; jj < 16; jj++)
            whr[jj] = *(const half8*)(wp + (((jj ^ qx) & 15) * 8));
    }
    half8 wwr[2][8]; // Ww rows 2*tid..+1, cols own 64 (row-slice for wvp partials)
    {
        const _Float16* wp = ww + (size_t)(tid * 2) * 1024 + s * 64;
        #pragma unroll
        for (int jj = 0; jj < 2; jj++)
            #pragma unroll
            for (int kk = 0; kk < 8; kk++)
                wwr[jj][kk] = *(const half8*)(wp + jj * 1024 + kk * 8);
    }
    // ---- replicated tape in registers: dims 2*tid..+1 for all 16 rows ----
    f32x2 tp[16];
    #pragma unroll
    for (int n = 0; n < 16; n++)
        tp[n] = *(const f32x2*)(&tape_in[(size_t)(g * 16 + n) * 1024 + tid * 2]);
    const float bhc = bh[s * 64 + cc];

    // ---- prologue: own h0 into h_prev ----
    {
        f32x2 h2 = *(const f32x2*)(&h_in[(size_t)g * 1024 + tid * 2]);
        half2_t hh; hh[0] = (_Float16)h2[0]; hh[1] = (_Float16)h2[1];
        *(half2_t*)(&h_prev[tid * 2]) = hh;
    }
    __syncthreads();

    u32* senrow = sen + (size_t)(g * 16 + s) * 32;
    const int senb = g * 16;

    for (int t = 0; t <= 512; t++) {
        char* srd  = ring + (size_t)(g * 8 + ((t + 7) & 7)) * SLOTB;  // slot (t-1)&7
        char* spub = ring + (size_t)(g * 8 + (t & 7)) * SLOTB;        // slot t&7
        const bool havew = (t >= 1);
        // early x_proj / z prefetch (8-redundant over q; hides under poll)
        float xp = 0.f, zz = 0.f;
        if (t < 512) {
            size_t m = (size_t)(g * 512 + t) * 2048 + s * 64 + cc;
            xp = (float)xz[m];
            zz = (float)xz[m + 1024];
        }
        f32x2 wv2 = (f32x2){0.f, 0.f};
        if (havew) {
            // ---- the single sync of the step: 16 parallel sentinel lines ----
            if (!dead && lane < 16) {
                int spin = 0;
                while (ldsen(&sen[(size_t)(senb + lane) * 32]) < (u32)t) {
                    if (++spin > 2000000) { dead = true; break; }
                    __builtin_amdgcn_s_sleep(1);
                }
            }
            asm volatile("" ::: "memory");
            // gather full h_{t-1} -> h_prev (read post-B1)
            if (tid < 128) {
                const u64* Hp = (const u64*)(srd + R_H);
                Pk2 u;
                u.u[0] = ldq(&Hp[tid * 2], mall);
                u.u[1] = ldq(&Hp[tid * 2 + 1], mall);
                *(half8*)(&h_prev[tid * 8]) = u.h8;
            }
            // wv all-reduce: own 2 dims from 16 producer slices (f16 packed, 4B each)
            const u32* Wp = (const u32*)(srd + R_WVP);
            #pragma unroll
            for (int sl = 0; sl < 16; sl++) {
                PkW u; u.u = ldw(&Wp[sl * 512 + tid], mall);
                wv2[0] += (float)u.h[0]; wv2[1] += (float)u.h[1];
            }
            // write-score partials (wv . tape entering step t-1)
            {
                float p[16];
                #pragma unroll
                for (int n = 0; n < 16; n++) {
                    f32x2 d = tp[n];
                    p[n] = wv2[0]*d[0] + wv2[1]*d[1];
                }
                #pragma unroll
                for (int n = 0; n < 16; n++) p_l[tid * 17 + n] = p[n];
            }
            __syncthreads();                                   // B1: p_l + h_prev ready
            {
                float scw = 0.f;
                #pragma unroll
                for (int m2 = 0; m2 < 16; m2++) scw += p_l[(c32 + 32 * m2) * 17 + nn];
                #pragma unroll
                for (int d2 = 1; d2 < 32; d2 <<= 1) scw += __shfl_xor(scw, d2, 32);
                if (c32 == 0) sc_l[nn] = scw;
            }
            __syncthreads();                                   // B2: sc_l ready
            {   // write softmax (redundant per thread) + lazy tape update
                float e[16], mxw = -1e30f;
                #pragma unroll
                for (int n = 0; n < 16; n++) { e[n] = sc_l[n] * SCALE; mxw = fmaxf(mxw, e[n]); }
                float smw = 0.f;
                #pragma unroll
                for (int n = 0; n < 16; n++) { e[n] = __expf(e[n] - mxw); smw += e[n]; }
                float invw = 1.f / smw;
                #pragma unroll
                for (int n = 0; n < 16; n++) {
                    float wan = e[n] * invw;
                    f32x2 d = tp[n];
                    d[0] += wan * (wv2[0] - d[0]);
                    d[1] += wan * (wv2[1] - d[1]);
                    tp[n] = d;
                }
            }
        }
        if (t == 512) break;   // finale: tape has write of step 511 applied

        // read-score partials (h_{t-1} . tape entering step t)
        {
            half2_t hh = *(const half2_t*)(&h_prev[tid * 2]);
            float h0 = (float)hh[0], h1 = (float)hh[1];
            float p[16];
            #pragma unroll
            for (int n = 0; n < 16; n++) {
                f32x2 d = tp[n];
                p[n] = h0*d[0] + h1*d[1];
            }
            #pragma unroll
            for (int n = 0; n < 16; n++) p_l[tid * 17 + n] = p[n];
        }
        __syncthreads();                                       // B3
        float sc = 0.f;
        #pragma unroll
        for (int m2 = 0; m2 < 16; m2++) sc += p_l[(c32 + 32 * m2) * 17 + nn];
        #pragma unroll
        for (int d2 = 1; d2 < 32; d2 <<= 1) sc += __shfl_xor(sc, d2, 32);
        if (c32 == 0) sc_l[nn] = sc;
        __syncthreads();                                       // B4
        float r[16], mx = -1e30f;
        #pragma unroll
        for (int n = 0; n < 16; n++) { r[n] = sc_l[n] * SCALE; mx = fmaxf(mx, r[n]); }
        float sm = 0.f;
        #pragma unroll
        for (int n = 0; n < 16; n++) { r[n] = __expf(r[n] - mx); sm += r[n]; }
        float inv = 1.f / sm;
        // read_val, own 2 dims (from register tape)
        f32x2 rv2 = (f32x2){0.f, 0.f};
        #pragma unroll
        for (int n = 0; n < 16; n++) {
            float ra = r[n] * inv;
            rv2[0] += ra * tp[n][0];
            rv2[1] += ra * tp[n][1];
        }
        *(f32x2*)(&rv_l[tid * 2]) = rv2;
        // Wh matvec (col-role): full h_{t-1} from LDS, xor'd chunk order
        float a0 = 0.f, a1 = 0.f, a2 = 0.f, a3 = 0.f;
        #pragma unroll
        for (int jj = 0; jj < 16; jj++) {
            half8 hp8 = *(const half8*)(&h_prev[q * 128 + (((jj ^ qx) & 15) * 8)]);
            half8 wc = whr[jj];
            FDOT(hp2(wc,0), hp2(hp8,0), a0);
            FDOT(hp2(wc,1), hp2(hp8,1), a1);
            FDOT(hp2(wc,2), hp2(hp8,2), a2);
            FDOT(hp2(wc,3), hp2(hp8,3), a3);
        }
        float av = (a0 + a1) + (a2 + a3);
        av += __shfl_xor(av, 1);
        av += __shfl_xor(av, 2);
        av += __shfl_xor(av, 4);
        __syncthreads();                                       // B5: rv_l ready
        float rd = rv_l[s * 64 + cc];
        float hv = tanhf(av + xp + rd + bhc);
        float g2 = zz + rd + hv;
        float o = hv * g2 / (1.f + __expf(-g2));
        if (q == 0) h_own[cc] = (_Float16)hv;
        __syncthreads();                                       // B6: h_own ready
        // wvp partials: rows 2*tid..+1 over own 64 k (h_own broadcast reads)
        half8 hr[8];
        #pragma unroll
        for (int kk = 0; kk < 8; kk++) hr[kk] = *(const half8*)(&h_own[kk * 8]);
        float w0 = 0.f, w1 = 0.f;
        #pragma unroll
        for (int kk = 0; kk < 8; kk++) {
            half8 h8 = hr[kk];
            #pragma unroll
            for (int pp = 0; pp < 4; pp++) {
                FDOT(hp2(wwr[0][kk],pp), hp2(h8,pp), w0);
                FDOT(hp2(wwr[1][kk],pp), hp2(h8,pp), w1);
            }
        }
        {   // publish wvp (packed f16 half2, 4B) + h slice into slot t&7
            PkW wq;
            wq.h = (half2_t){(_Float16)w0, (_Float16)w1};
            stw(&((u32*)(spub + R_WVP))[s * 512 + tid], wq.u, mall);
            if (tid < 8) {
                Pk2 u; u.h8 = *(const half8*)(&h_own[tid * 8]);
                u64* Hp = (u64*)(spub + R_H);
                stq(&Hp[s * 16 + tid * 2],     u.u[0], mall);
                stq(&Hp[s * 16 + tid * 2 + 1], u.u[1], mall);
            }
        }
        __syncthreads();                                       // B7: vmcnt drain (h + wvp)
        if (tid == 0) stsen(senrow, (u32)(t + 1));
        // deferred out store (off the sentinel critical path)
        if (q == 0) out[(size_t)(g * 512 + t) * 1024 + s * 64 + cc] = o;
    }
    // ================= finale: write h_tape_final (slice 0 of each group) =================
    if (s == 0) {
        #pragma unroll
        for (int n = 0; n < 16; n++)
            *(f32x2*)(&out[8388608ULL + (size_t)(g * 16 + n) * 1024 + tid * 2]) = tp[n];
    }
}

extern "C" void kernel_launch(void* const* d_in, const int* in_sizes, int n_in,
                              void* d_out, int out_size, void* d_ws, size_t ws_size,
                              hipStream_t stream) {
    const float* x     = (const float*)d_in[0];
    const float* tape0 = (const float*)d_in[1];
    const float* h0    = (const float*)d_in[2];
    const float* Wh    = (const float*)d_in[3];
    const float* Wxz   = (const float*)d_in[4];
    const float* bh    = (const float*)d_in[5];
    const float* Ww    = (const float*)d_in[6];

    char* ws = (char*)d_ws;
    _Float16* xbf   = (_Float16*)(ws + XBF_OFF);
    _Float16* wxzbf = (_Float16*)(ws + WXZ_OFF);
    _Float16* whbf  = (_Float16*)(ws + WH_OFF);
    _Float16* wwbf  = (_Float16*)(ws + WW_OFF);
    _Float16* xzbf  = (_Float16*)(ws + XZ_OFF);
    char* ring      = ws + RING_OFF;
    u32* vote       = (u32*)(ws + VOTE_OFF);
    u32* sen        = (u32*)(ws + SEN_OFF);

    // vote (4 KB) + sentinels (32 KB): zeroed every launch
    hipMemsetAsync(ws + VOTE_OFF, 0, 4096 + 32768, stream);

    cvt_kernel<<<8192, 256, 0, stream>>>(x, xbf, 2097152);
    cvt_kernel<<<2048, 256, 0, stream>>>(Wxz, wxzbf, 524288);
    cvt_kernel<<<1024, 256, 0, stream>>>(Wh, whbf, 262144);
    cvt_kernel<<<1024, 256, 0, stream>>>(Ww, wwbf, 262144);

    gemm_xz<<<dim3(16, 64), 256, 0, stream>>>(xbf, wxzbf, xzbf);

    scan_kernel<<<256, 512, 0, stream>>>(xzbf, tape0, h0, bh, whbf, wwbf,
                                         ring, sen, vote, (float*)d_out);
}

// Round 12
// 2700.889 us; speedup vs baseline: 1.5260x; 1.0007x over previous
//
#include <hip/hip_runtime.h>

typedef _Float16 half8 __attribute__((ext_vector_type(8)));
typedef _Float16 half4_t __attribute__((ext_vector_type(4)));
typedef _Float16 half2_t __attribute__((ext_vector_type(2)));
typedef float f32x4 __attribute__((ext_vector_type(4)));
typedef float f32x2 __attribute__((ext_vector_type(2)));
typedef unsigned long long u64;
typedef unsigned int u32;

#define SCALE 0.03125f   // 1/sqrt(1024)

// workspace layout (bytes)
#define XZ_OFF   0ULL            // f16 [8192][2048]  33,554,432
#define RING_OFF 33554432ULL     // ring: 16 groups x 8 slots x 36,864 B (xbf reused)
#define XBF_OFF  33554432ULL     // x f16 (pre-scan only; overlays ring)
#define WXZ_OFF  50331648ULL     // f16 [2048][1024]   4,194,304
#define WH_OFF   54525952ULL     // f16 [1024][1024]   2,097,152
#define WW_OFF   56623104ULL     // f16 [1024][1024]   2,097,152
#define VOTE_OFF 58720256ULL     // u32 [256][4] = 4096   (memset'd)
#define SEN_OFF  58724352ULL     // u32 [256][32] (128B stride) = 32768 (memset'd)

// ring slot internals: per (group, slot)
#define SLOTB 36864ULL
#define R_WVP 0        // f16 [16 slices][1024]  32,768  (packed half2 per thread)
#define R_H   32768    // f16 [1024]              2,048

union Pk2 { u64 u[2]; half8 h8; };
union PkW { u32 u; half2_t h; };

// ---- transport helpers: uniform `mall` flag picks MALL vs same-XCD L2 (proven) ----
__device__ __forceinline__ u64 ldq(const u64* p, bool mall) {
    return mall ? __hip_atomic_load(p, __ATOMIC_RELAXED, __HIP_MEMORY_SCOPE_AGENT) : *p;
}
__device__ __forceinline__ void stq(u64* p, u64 v, bool mall) {
    if (mall) __hip_atomic_store(p, v, __ATOMIC_RELAXED, __HIP_MEMORY_SCOPE_AGENT); else *p = v;
}
__device__ __forceinline__ u32 ldw(const u32* p, bool mall) {
    return mall ? __hip_atomic_load(p, __ATOMIC_RELAXED, __HIP_MEMORY_SCOPE_AGENT) : *p;
}
__device__ __forceinline__ void stw(u32* p, u32 v, bool mall) {
    if (mall) __hip_atomic_store(p, v, __ATOMIC_RELAXED, __HIP_MEMORY_SCOPE_AGENT); else *p = v;
}
// sentinels: relaxed AGENT atomics on 16 INDEPENDENT 128B-strided lines
// (parallel-line poll; R9's single accumulating counter serialized 16 RMWs
// on one TCC line and cost ~+145us)
__device__ __forceinline__ u32 ldsen(u32* p) {
    return __hip_atomic_load(p, __ATOMIC_RELAXED, __HIP_MEMORY_SCOPE_AGENT);
}
__device__ __forceinline__ void stsen(u32* p, u32 v) {
    __hip_atomic_store(p, v, __ATOMIC_RELAXED, __HIP_MEMORY_SCOPE_AGENT);
}

#define FDOT(a,b,acc) acc = __builtin_amdgcn_fdot2((a),(b),(acc),false)
__device__ __forceinline__ half2_t hp2(half8 v, int i) {
    half2_t r; r[0] = v[2*i]; r[1] = v[2*i+1]; return r;
}

__global__ void cvt_kernel(const float* __restrict__ in, _Float16* __restrict__ o, int n4) {
    int i = blockIdx.x * 256 + threadIdx.x;
    if (i < n4) {
        f32x4 v = ((const f32x4*)in)[i];
        half4_t h;
        h[0] = (_Float16)v[0]; h[1] = (_Float16)v[1];
        h[2] = (_Float16)v[2]; h[3] = (_Float16)v[3];
        ((half4_t*)o)[i] = h;
    }
}

// xz[m][n] = sum_k x[m][k] * Wxz[n][k];  M=8192, N=2048, K=1024  (unchanged, proven)
__launch_bounds__(256, 1)
__global__ void gemm_xz(const _Float16* __restrict__ A,
                        const _Float16* __restrict__ Bw,
                        _Float16* __restrict__ C) {
    __shared__ _Float16 As[128 * 40];
    __shared__ _Float16 Bs[128 * 40];
    const int tid = threadIdx.x;
    const int m0 = blockIdx.y * 128, n0 = blockIdx.x * 128;
    const int w = tid >> 6, lane = tid & 63;
    const int mw = (w >> 1) * 64, nw = (w & 1) * 64;
    const int row = lane & 15, q = lane >> 4;
    f32x4 acc[4][4];
    #pragma unroll
    for (int mt = 0; mt < 4; mt++)
        #pragma unroll
        for (int nt = 0; nt < 4; nt++)
            acc[mt][nt] = (f32x4){0.f, 0.f, 0.f, 0.f};

    for (int k0 = 0; k0 < 1024; k0 += 32) {
        __syncthreads();
        for (int cc = tid; cc < 512; cc += 256) {
            int r = cc >> 2, kc = (cc & 3) * 8;
            *(half8*)(&As[r * 40 + kc]) = *(const half8*)(&A[(size_t)(m0 + r) * 1024 + k0 + kc]);
            *(half8*)(&Bs[r * 40 + kc]) = *(const half8*)(&Bw[(size_t)(n0 + r) * 1024 + k0 + kc]);
        }
        __syncthreads();
        half8 af[4], bf[4];
        #pragma unroll
        for (int mt = 0; mt < 4; mt++) af[mt] = *(const half8*)(&As[(mw + mt * 16 + row) * 40 + q * 8]);
        #pragma unroll
        for (int nt = 0; nt < 4; nt++) bf[nt] = *(const half8*)(&Bs[(nw + nt * 16 + row) * 40 + q * 8]);
        #pragma unroll
        for (int mt = 0; mt < 4; mt++)
            #pragma unroll
            for (int nt = 0; nt < 4; nt++)
                acc[mt][nt] = __builtin_amdgcn_mfma_f32_16x16x32_f16(af[mt], bf[nt], acc[mt][nt], 0, 0, 0);
    }
    #pragma unroll
    for (int mt = 0; mt < 4; mt++)
        #pragma unroll
        for (int nt = 0; nt < 4; nt++)
            #pragma unroll
            for (int r = 0; r < 4; r++) {
                int gm = m0 + mw + mt * 16 + q * 4 + r;
                int gn = n0 + nw + nt * 16 + row;
                C[(size_t)gm * 2048 + gn] = (_Float16)acc[mt][nt][r];
            }
}

// Batch-partitioned persistent scan — R10 (proven 2702us) + ONE knob:
// amdgpu_waves_per_eu(2,2).  R10's allocator targeted 4 waves/EU (VGPR=128)
// but the 81KB LDS pad caps the CU at 1 block = 2 waves/EU -- half the
// register budget was wasted while whr/wwr/tp (160 VGPRs) were re-streamed
// from L1/L2 every step.  Telling the allocator the true occupancy raises
// the cap to 256 VGPRs/wave so the weights are genuinely pinned.
__launch_bounds__(512)
__attribute__((amdgpu_waves_per_eu(2, 2)))
__global__ void scan_kernel(const _Float16* __restrict__ xz,   // [8192][2048] f16
                            const float* __restrict__ tape_in, // [16][16][1024]
                            const float* __restrict__ h_in,    // [16][1024]
                            const float* __restrict__ bh,      // [1024]
                            const _Float16* __restrict__ wh,   // [1024][1024] f16
                            const _Float16* __restrict__ ww,   // [1024][1024] f16
                            char* ring,                        // 16 groups x 8 slots x SLOTB
                            u32* sen,                          // [256][32]
                            u32* vote,                         // [256][4]
                            float* __restrict__ out) {
    const int bx = blockIdx.x;
    const int g = (bx & 7) * 2 + ((bx >> 3) & 1);   // batch group 0..15
    const int s = bx >> 4;                           // dim slice 0..15 (cols s*64..+63)
    const int tid = threadIdx.x;                     // 0..511
    const int lane = tid & 63;
    const int cc = tid >> 3, q = tid & 7;            // col-role: col cc (0..63), k-eighth q
    const int nn = tid >> 5, c32 = tid & 31;         // reducer role (16 rows x 32 threads)

    __shared__ __align__(16) _Float16 h_prev[1024];  // full h_{t-1}, f16
    __shared__ __align__(16) _Float16 h_own[64];     // own slice of h_t
    __shared__ __align__(16) float rv_l[1024];       // read_val (global dim order)
    __shared__ float p_l[512 * 17];                  // score partials (pad 17)
    __shared__ float sc_l[16];
    __shared__ float pad_l[10000];                   // LDS > 80 KiB: force 1 block/CU
    __shared__ int sh_same;

    { volatile float* vp = pad_l; vp[tid] = 0.f; }   // keep pad alive

    // ---- per-group XCC vote (memset-initialized) ----
    if (tid == 0) {
        u32 xcc;
        asm volatile("s_getreg_b32 %0, hwreg(HW_REG_XCC_ID)" : "=s"(xcc));
        xcc &= 7u;
        __hip_atomic_store(&vote[bx * 4], xcc + 1u, __ATOMIC_RELAXED, __HIP_MEMORY_SCOPE_AGENT);
        int same = 1; u32 ref = 0;
        for (int m = 0; m < 16; m++) {
            int mb = m * 16 + ((g & 1) << 3) + (g >> 1);   // group member blockIdx
            u32 v; int spin = 0;
            while ((v = __hip_atomic_load(&vote[mb * 4], __ATOMIC_RELAXED, __HIP_MEMORY_SCOPE_AGENT)) == 0u) {
                if (++spin > 1000000) { v = 0xFFFFFFFFu; break; }
                __builtin_amdgcn_s_sleep(2);
            }
            if (m == 0) ref = v;
            if (v != ref || v == 0xFFFFFFFFu) same = 0;
        }
        sh_same = same;
    }
    __syncthreads();
    const bool mall = (sh_same == 0);
    bool dead = false;

    // ---- pinned weights (fit in VGPRs at 512-thread split + waves_per_eu(2,2)) ----
    const int qx = q << 1;
    half8 whr[16];   // Wh[col s*64+cc][k-eighth q], chunk order xor'd (bank-spread)
    {
        const _Float16* wp = wh + (size_t)(s * 64 + cc) * 1024 + q * 128;
        #pragma unroll
        for (int jj = 0; jj < 16; jj++)
            whr[jj] = *(const half8*)(wp + (((jj ^ qx) & 15) * 8));
    }
    half8 wwr[2][8]; // Ww rows 2*tid..+1, cols own 64 (row-slice for wvp partials)
    {
        const _Float16* wp = ww + (size_t)(tid * 2) * 1024 + s * 64;
        #pragma unroll
        for (int jj = 0; jj < 2; jj++)
            #pragma unroll
            for (int kk = 0; kk < 8; kk++)
                wwr[jj][kk] = *(const half8*)(wp + jj * 1024 + kk * 8);
    }
    // ---- replicated tape in registers: dims 2*tid..+1 for all 16 rows ----
    f32x2 tp[16];
    #pragma unroll
    for (int n = 0; n < 16; n++)
        tp[n] = *(const f32x2*)(&tape_in[(size_t)(g * 16 + n) * 1024 + tid * 2]);
    const float bhc = bh[s * 64 + cc];

    // ---- prologue: own h0 into h_prev ----
    {
        f32x2 h2 = *(const f32x2*)(&h_in[(size_t)g * 1024 + tid * 2]);
        half2_t hh; hh[0] = (_Float16)h2[0]; hh[1] = (_Float16)h2[1];
        *(half2_t*)(&h_prev[tid * 2]) = hh;
    }
    __syncthreads();

    u32* senrow = sen + (size_t)(g * 16 + s) * 32;
    const int senb = g * 16;

    for (int t = 0; t <= 512; t++) {
        char* srd  = ring + (size_t)(g * 8 + ((t + 7) & 7)) * SLOTB;  // slot (t-1)&7
        char* spub = ring + (size_t)(g * 8 + (t & 7)) * SLOTB;        // slot t&7
        const bool havew = (t >= 1);
        // early x_proj / z prefetch (8-redundant over q; hides under poll)
        float xp = 0.f, zz = 0.f;
        if (t < 512) {
            size_t m = (size_t)(g * 512 + t) * 2048 + s * 64 + cc;
            xp = (float)xz[m];
            zz = (float)xz[m + 1024];
        }
        f32x2 wv2 = (f32x2){0.f, 0.f};
        if (havew) {
            // ---- the single sync of the step: 16 parallel sentinel lines ----
            if (!dead && lane < 16) {
                int spin = 0;
                while (ldsen(&sen[(size_t)(senb + lane) * 32]) < (u32)t) {
                    if (++spin > 2000000) { dead = true; break; }
                    __builtin_amdgcn_s_sleep(1);
                }
            }
            asm volatile("" ::: "memory");
            // gather full h_{t-1} -> h_prev (read post-B1)
            if (tid < 128) {
                const u64* Hp = (const u64*)(srd + R_H);
                Pk2 u;
                u.u[0] = ldq(&Hp[tid * 2], mall);
                u.u[1] = ldq(&Hp[tid * 2 + 1], mall);
                *(half8*)(&h_prev[tid * 8]) = u.h8;
            }
            // wv all-reduce: own 2 dims from 16 producer slices (f16 packed, 4B each)
            const u32* Wp = (const u32*)(srd + R_WVP);
            #pragma unroll
            for (int sl = 0; sl < 16; sl++) {
                PkW u; u.u = ldw(&Wp[sl * 512 + tid], mall);
                wv2[0] += (float)u.h[0]; wv2[1] += (float)u.h[1];
            }
            // write-score partials (wv . tape entering step t-1)
            {
                float p[16];
                #pragma unroll
                for (int n = 0; n < 16; n++) {
                    f32x2 d = tp[n];
                    p[n] = wv2[0]*d[0] + wv2[1]*d[1];
                }
                #pragma unroll
                for (int n = 0; n < 16; n++) p_l[tid * 17 + n] = p[n];
            }
            __syncthreads();                                   // B1: p_l + h_prev ready
            {
                float scw = 0.f;
                #pragma unroll
                for (int m2 = 0; m2 < 16; m2++) scw += p_l[(c32 + 32 * m2) * 17 + nn];
                #pragma unroll
                for (int d2 = 1; d2 < 32; d2 <<= 1) scw += __shfl_xor(scw, d2, 32);
                if (c32 == 0) sc_l[nn] = scw;
            }
            __syncthreads();                                   // B2: sc_l ready
            {   // write softmax (redundant per thread) + lazy tape update
                float e[16], mxw = -1e30f;
                #pragma unroll
                for (int n = 0; n < 16; n++) { e[n] = sc_l[n] * SCALE; mxw = fmaxf(mxw, e[n]); }
                float smw = 0.f;
                #pragma unroll
                for (int n = 0; n < 16; n++) { e[n] = __expf(e[n] - mxw); smw += e[n]; }
                float invw = 1.f / smw;
                #pragma unroll
                for (int n = 0; n < 16; n++) {
                    float wan = e[n] * invw;
                    f32x2 d = tp[n];
                    d[0] += wan * (wv2[0] - d[0]);
                    d[1] += wan * (wv2[1] - d[1]);
                    tp[n] = d;
                }
            }
        }
        if (t == 512) break;   // finale: tape has write of step 511 applied

        // read-score partials (h_{t-1} . tape entering step t)
        {
            half2_t hh = *(const half2_t*)(&h_prev[tid * 2]);
            float h0 = (float)hh[0], h1 = (float)hh[1];
            float p[16];
            #pragma unroll
            for (int n = 0; n < 16; n++) {
                f32x2 d = tp[n];
                p[n] = h0*d[0] + h1*d[1];
            }
            #pragma unroll
            for (int n = 0; n < 16; n++) p_l[tid * 17 + n] = p[n];
        }
        __syncthreads();                                       // B3
        float sc = 0.f;
        #pragma unroll
        for (int m2 = 0; m2 < 16; m2++) sc += p_l[(c32 + 32 * m2) * 17 + nn];
        #pragma unroll
        for (int d2 = 1; d2 < 32; d2 <<= 1) sc += __shfl_xor(sc, d2, 32);
        if (c32 == 0) sc_l[nn] = sc;
        __syncthreads();                                       // B4
        float r[16], mx = -1e30f;
        #pragma unroll
        for (int n = 0; n < 16; n++) { r[n] = sc_l[n] * SCALE; mx = fmaxf(mx, r[n]); }
        float sm = 0.f;
        #pragma unroll
        for (int n = 0; n < 16; n++) { r[n] = __expf(r[n] - mx); sm += r[n]; }
        float inv = 1.f / sm;
        // read_val, own 2 dims (from register tape)
        f32x2 rv2 = (f32x2){0.f, 0.f};
        #pragma unroll
        for (int n = 0; n < 16; n++) {
            float ra = r[n] * inv;
            rv2[0] += ra * tp[n][0];
            rv2[1] += ra * tp[n][1];
        }
        *(f32x2*)(&rv_l[tid * 2]) = rv2;
        // Wh matvec (col-role): full h_{t-1} from LDS, xor'd chunk order
        float a0 = 0.f, a1 = 0.f, a2 = 0.f, a3 = 0.f;
        #pragma unroll
        for (int jj = 0; jj < 16; jj++) {
            half8 hp8 = *(const half8*)(&h_prev[q * 128 + (((jj ^ qx) & 15) * 8)]);
            half8 wc = whr[jj];
            FDOT(hp2(wc,0), hp2(hp8,0), a0);
            FDOT(hp2(wc,1), hp2(hp8,1), a1);
            FDOT(hp2(wc,2), hp2(hp8,2), a2);
            FDOT(hp2(wc,3), hp2(hp8,3), a3);
        }
        float av = (a0 + a1) + (a2 + a3);
        av += __shfl_xor(av, 1);
        av += __shfl_xor(av, 2);
        av += __shfl_xor(av, 4);
        __syncthreads();                                       // B5: rv_l ready
        float rd = rv_l[s * 64 + cc];
        float hv = tanhf(av + xp + rd + bhc);
        float g2 = zz + rd + hv;
        float o = hv * g2 / (1.f + __expf(-g2));
        if (q == 0) h_own[cc] = (_Float16)hv;
        __syncthreads();                                       // B6: h_own ready
        // wvp partials: rows 2*tid..+1 over own 64 k (h_own broadcast reads)
        half8 hr[8];
        #pragma unroll
        for (int kk = 0; kk < 8; kk++) hr[kk] = *(const half8*)(&h_own[kk * 8]);
        float w0 = 0.f, w1 = 0.f;
        #pragma unroll
        for (int kk = 0; kk < 8; kk++) {
            half8 h8 = hr[kk];
            #pragma unroll
            for (int pp = 0; pp < 4; pp++) {
                FDOT(hp2(wwr[0][kk],pp), hp2(h8,pp), w0);
                FDOT(hp2(wwr[1][kk],pp), hp2(h8,pp), w1);
            }
        }
        {   // publish wvp (packed f16 half2, 4B) + h slice into slot t&7
            PkW wq;
            wq.h = (half2_t){(_Float16)w0, (_Float16)w1};
            stw(&((u32*)(spub + R_WVP))[s * 512 + tid], wq.u, mall);
            if (tid < 8) {
                Pk2 u; u.h8 = *(const half8*)(&h_own[tid * 8]);
                u64* Hp = (u64*)(spub + R_H);
                stq(&Hp[s * 16 + tid * 2],     u.u[0], mall);
                stq(&Hp[s * 16 + tid * 2 + 1], u.u[1], mall);
            }
        }
        __syncthreads();                                       // B7: vmcnt drain (h + wvp)
        if (tid == 0) stsen(senrow, (u32)(t + 1));
        // deferred out store (off the sentinel critical path)
        if (q == 0) out[(size_t)(g * 512 + t) * 1024 + s * 64 + cc] = o;
    }
    // ================= finale: write h_tape_final (slice 0 of each group) =================
    if (s == 0) {
        #pragma unroll
        for (int n = 0; n < 16; n++)
            *(f32x2*)(&out[8388608ULL + (size_t)(g * 16 + n) * 1024 + tid * 2]) = tp[n];
    }
}

extern "C" void kernel_launch(void* const* d_in, const int* in_sizes, int n_in,
                              void* d_out, int out_size, void* d_ws, size_t ws_size,
                              hipStream_t stream) {
    const float* x     = (const float*)d_in[0];
    const float* tape0 = (const float*)d_in[1];
    const float* h0    = (const float*)d_in[2];
    const float* Wh    = (const float*)d_in[3];
    const float* Wxz   = (const float*)d_in[4];
    const float* bh    = (const float*)d_in[5];
    const float* Ww    = (const float*)d_in[6];

    char* ws = (char*)d_ws;
    _Float16* xbf   = (_Float16*)(ws + XBF_OFF);
    _Float16* wxzbf = (_Float16*)(ws + WXZ_OFF);
    _Float16* whbf  = (_Float16*)(ws + WH_OFF);
    _Float16* wwbf  = (_Float16*)(ws + WW_OFF);
    _Float16* xzbf  = (_Float16*)(ws + XZ_OFF);
    char* ring      = ws + RING_OFF;
    u32* vote       = (u32*)(ws + VOTE_OFF);
    u32* sen        = (u32*)(ws + SEN_OFF);

    // vote (4 KB) + sentinels (32 KB): zeroed every launch
    hipMemsetAsync(ws + VOTE_OFF, 0, 4096 + 32768, stream);

    cvt_kernel<<<8192, 256, 0, stream>>>(x, xbf, 2097152);
    cvt_kernel<<<2048, 256, 0, stream>>>(Wxz, wxzbf, 524288);
    cvt_kernel<<<1024, 256, 0, stream>>>(Wh, whbf, 262144);
    cvt_kernel<<<1024, 256, 0, stream>>>(Ww, wwbf, 262144);

    gemm_xz<<<dim3(16, 64), 256, 0, stream>>>(xbf, wxzbf, xzbf);

    scan_kernel<<<256, 512, 0, stream>>>(xzbf, tape0, h0, bh, whbf, wwbf,
                                         ring, sen, vote, (float*)d_out);
}

// Round 13
// 2695.776 us; speedup vs baseline: 1.5289x; 1.0019x over previous
//
#include <hip/hip_runtime.h>

typedef _Float16 half8 __attribute__((ext_vector_type(8)));
typedef _Float16 half4_t __attribute__((ext_vector_type(4)));
typedef _Float16 half2_t __attribute__((ext_vector_type(2)));
typedef float f32x4 __attribute__((ext_vector_type(4)));
typedef float f32x2 __attribute__((ext_vector_type(2)));
typedef unsigned long long u64;
typedef unsigned int u32;

#define SCALE 0.03125f   // 1/sqrt(1024)

// workspace layout (bytes)
#define XZ_OFF   0ULL            // f16 [8192][2048]  33,554,432
#define RING_OFF 33554432ULL     // ring: 16 groups x 8 slots x 36,864 B (xbf reused)
#define XBF_OFF  33554432ULL     // x f16 (pre-scan only; overlays ring)
#define WXZ_OFF  50331648ULL     // f16 [2048][1024]   4,194,304
#define WH_OFF   54525952ULL     // f16 [1024][1024]   2,097,152
#define WW_OFF   56623104ULL     // f16 [1024][1024]   2,097,152
#define VOTE_OFF 58720256ULL     // u32 [256][4] = 4096   (memset'd)
#define SEN_OFF  58724352ULL     // u32 [256][32] (128B stride) = 32768 (memset'd)

// ring slot internals: per (group, slot)
#define SLOTB 36864ULL
#define R_WVP 0        // f16 [16 slices][1024]  32,768  (packed half2 per thread)
#define R_H   32768    // f16 [1024]              2,048

union Pk2 { u64 u[2]; half8 h8; };
union PkW { u32 u; half2_t h; };

// ---- transport helpers: uniform `mall` flag picks MALL vs same-XCD L2 (proven) ----
__device__ __forceinline__ u64 ldq(const u64* p, bool mall) {
    return mall ? __hip_atomic_load(p, __ATOMIC_RELAXED, __HIP_MEMORY_SCOPE_AGENT) : *p;
}
__device__ __forceinline__ void stq(u64* p, u64 v, bool mall) {
    if (mall) __hip_atomic_store(p, v, __ATOMIC_RELAXED, __HIP_MEMORY_SCOPE_AGENT); else *p = v;
}
__device__ __forceinline__ u32 ldw(const u32* p, bool mall) {
    return mall ? __hip_atomic_load(p, __ATOMIC_RELAXED, __HIP_MEMORY_SCOPE_AGENT) : *p;
}
__device__ __forceinline__ void stw(u32* p, u32 v, bool mall) {
    if (mall) __hip_atomic_store(p, v, __ATOMIC_RELAXED, __HIP_MEMORY_SCOPE_AGENT); else *p = v;
}
// sentinels: relaxed AGENT atomics on 16 INDEPENDENT 128B-strided lines
// (parallel-line poll; R9's single accumulating counter serialized 16 RMWs
// on one TCC line and cost ~+145us)
__device__ __forceinline__ u32 ldsen(u32* p) {
    return __hip_atomic_load(p, __ATOMIC_RELAXED, __HIP_MEMORY_SCOPE_AGENT);
}
__device__ __forceinline__ void stsen(u32* p, u32 v) {
    __hip_atomic_store(p, v, __ATOMIC_RELAXED, __HIP_MEMORY_SCOPE_AGENT);
}

#define FDOT(a,b,acc) acc = __builtin_amdgcn_fdot2((a),(b),(acc),false)
__device__ __forceinline__ half2_t hp2(half8 v, int i) {
    half2_t r; r[0] = v[2*i]; r[1] = v[2*i+1]; return r;
}

__global__ void cvt_kernel(const float* __restrict__ in, _Float16* __restrict__ o, int n4) {
    int i = blockIdx.x * 256 + threadIdx.x;
    if (i < n4) {
        f32x4 v = ((const f32x4*)in)[i];
        half4_t h;
        h[0] = (_Float16)v[0]; h[1] = (_Float16)v[1];
        h[2] = (_Float16)v[2]; h[3] = (_Float16)v[3];
        ((half4_t*)o)[i] = h;
    }
}

// xz[m][n] = sum_k x[m][k] * Wxz[n][k];  M=8192, N=2048, K=1024  (unchanged, proven)
__launch_bounds__(256, 1)
__global__ void gemm_xz(const _Float16* __restrict__ A,
                        const _Float16* __restrict__ Bw,
                        _Float16* __restrict__ C) {
    __shared__ _Float16 As[128 * 40];
    __shared__ _Float16 Bs[128 * 40];
    const int tid = threadIdx.x;
    const int m0 = blockIdx.y * 128, n0 = blockIdx.x * 128;
    const int w = tid >> 6, lane = tid & 63;
    const int mw = (w >> 1) * 64, nw = (w & 1) * 64;
    const int row = lane & 15, q = lane >> 4;
    f32x4 acc[4][4];
    #pragma unroll
    for (int mt = 0; mt < 4; mt++)
        #pragma unroll
        for (int nt = 0; nt < 4; nt++)
            acc[mt][nt] = (f32x4){0.f, 0.f, 0.f, 0.f};

    for (int k0 = 0; k0 < 1024; k0 += 32) {
        __syncthreads();
        for (int cc = tid; cc < 512; cc += 256) {
            int r = cc >> 2, kc = (cc & 3) * 8;
            *(half8*)(&As[r * 40 + kc]) = *(const half8*)(&A[(size_t)(m0 + r) * 1024 + k0 + kc]);
            *(half8*)(&Bs[r * 40 + kc]) = *(const half8*)(&Bw[(size_t)(n0 + r) * 1024 + k0 + kc]);
        }
        __syncthreads();
        half8 af[4], bf[4];
        #pragma unroll
        for (int mt = 0; mt < 4; mt++) af[mt] = *(const half8*)(&As[(mw + mt * 16 + row) * 40 + q * 8]);
        #pragma unroll
        for (int nt = 0; nt < 4; nt++) bf[nt] = *(const half8*)(&Bs[(nw + nt * 16 + row) * 40 + q * 8]);
        #pragma unroll
        for (int mt = 0; mt < 4; mt++)
            #pragma unroll
            for (int nt = 0; nt < 4; nt++)
                acc[mt][nt] = __builtin_amdgcn_mfma_f32_16x16x32_f16(af[mt], bf[nt], acc[mt][nt], 0, 0, 0);
    }
    #pragma unroll
    for (int mt = 0; mt < 4; mt++)
        #pragma unroll
        for (int nt = 0; nt < 4; nt++)
            #pragma unroll
            for (int r = 0; r < 4; r++) {
                int gm = m0 + mw + mt * 16 + q * 4 + r;
                int gn = n0 + nw + nt * 16 + row;
                C[(size_t)gm * 2048 + gn] = (_Float16)acc[mt][nt][r];
            }
}

// Batch-partitioned persistent scan — R10 (proven 2702us) + ONE knob, now in
// the DOCUMENTED spelling: __launch_bounds__(512, 2).  Second arg = min waves
// per EU on AMD; with the 81KB LDS pad already capping the CU at 1 block
// (2 waves/EU), this tells the allocator the truth and raises the per-wave
// VGPR budget to 256 so whr/wwr/tp (160 VGPRs) can actually stay resident.
// (R12's __attribute__((amdgpu_waves_per_eu(2,2))) was ignored: VGPR stayed
// 128, counters byte-identical.)
__launch_bounds__(512, 2)
__global__ void scan_kernel(const _Float16* __restrict__ xz,   // [8192][2048] f16
                            const float* __restrict__ tape_in, // [16][16][1024]
                            const float* __restrict__ h_in,    // [16][1024]
                            const float* __restrict__ bh,      // [1024]
                            const _Float16* __restrict__ wh,   // [1024][1024] f16
                            const _Float16* __restrict__ ww,   // [1024][1024] f16
                            char* ring,                        // 16 groups x 8 slots x SLOTB
                            u32* sen,                          // [256][32]
                            u32* vote,                         // [256][4]
                            float* __restrict__ out) {
    const int bx = blockIdx.x;
    const int g = (bx & 7) * 2 + ((bx >> 3) & 1);   // batch group 0..15
    const int s = bx >> 4;                           // dim slice 0..15 (cols s*64..+63)
    const int tid = threadIdx.x;                     // 0..511
    const int lane = tid & 63;
    const int cc = tid >> 3, q = tid & 7;            // col-role: col cc (0..63), k-eighth q
    const int nn = tid >> 5, c32 = tid & 31;         // reducer role (16 rows x 32 threads)

    __shared__ __align__(16) _Float16 h_prev[1024];  // full h_{t-1}, f16
    __shared__ __align__(16) _Float16 h_own[64];     // own slice of h_t
    __shared__ __align__(16) float rv_l[1024];       // read_val (global dim order)
    __shared__ float p_l[512 * 17];                  // score partials (pad 17)
    __shared__ float sc_l[16];
    __shared__ float pad_l[10000];                   // LDS > 80 KiB: force 1 block/CU
    __shared__ int sh_same;

    { volatile float* vp = pad_l; vp[tid] = 0.f; }   // keep pad alive

    // ---- per-group XCC vote (memset-initialized) ----
    if (tid == 0) {
        u32 xcc;
        asm volatile("s_getreg_b32 %0, hwreg(HW_REG_XCC_ID)" : "=s"(xcc));
        xcc &= 7u;
        __hip_atomic_store(&vote[bx * 4], xcc + 1u, __ATOMIC_RELAXED, __HIP_MEMORY_SCOPE_AGENT);
        int same = 1; u32 ref = 0;
        for (int m = 0; m < 16; m++) {
            int mb = m * 16 + ((g & 1) << 3) + (g >> 1);   // group member blockIdx
            u32 v; int spin = 0;
            while ((v = __hip_atomic_load(&vote[mb * 4], __ATOMIC_RELAXED, __HIP_MEMORY_SCOPE_AGENT)) == 0u) {
                if (++spin > 1000000) { v = 0xFFFFFFFFu; break; }
                __builtin_amdgcn_s_sleep(2);
            }
            if (m == 0) ref = v;
            if (v != ref || v == 0xFFFFFFFFu) same = 0;
        }
        sh_same = same;
    }
    __syncthreads();
    const bool mall = (sh_same == 0);
    bool dead = false;

    // ---- pinned weights (fit in VGPRs at 512-thread split + launch_bounds(512,2)) ----
    const int qx = q << 1;
    half8 whr[16];   // Wh[col s*64+cc][k-eighth q], chunk order xor'd (bank-spread)
    {
        const _Float16* wp = wh + (size_t)(s * 64 + cc) * 1024 + q * 128;
        #pragma unroll
        for (int jj = 0; jj < 16; jj++)
            whr[jj] = *(const half8*)(wp + (((jj ^ qx) & 15) * 8));
    }
    half8 wwr[2][8]; // Ww rows 2*tid..+1, cols own 64 (row-slice for wvp partials)
    {
        const _Float16* wp = ww + (size_t)(tid * 2) * 1024 + s * 64;
        #pragma unroll
        for (int jj = 0; jj < 2; jj++)
            #pragma unroll
            for (int kk = 0; kk < 8; kk++)
                wwr[jj][kk] = *(const half8*)(wp + jj * 1024 + kk * 8);
    }
    // ---- replicated tape in registers: dims 2*tid..+1 for all 16 rows ----
    f32x2 tp[16];
    #pragma unroll
    for (int n = 0; n < 16; n++)
        tp[n] = *(const f32x2*)(&tape_in[(size_t)(g * 16 + n) * 1024 + tid * 2]);
    const float bhc = bh[s * 64 + cc];

    // ---- prologue: own h0 into h_prev ----
    {
        f32x2 h2 = *(const f32x2*)(&h_in[(size_t)g * 1024 + tid * 2]);
        half2_t hh; hh[0] = (_Float16)h2[0]; hh[1] = (_Float16)h2[1];
        *(half2_t*)(&h_prev[tid * 2]) = hh;
    }
    __syncthreads();

    u32* senrow = sen + (size_t)(g * 16 + s) * 32;
    const int senb = g * 16;

    for (int t = 0; t <= 512; t++) {
        char* srd  = ring + (size_t)(g * 8 + ((t + 7) & 7)) * SLOTB;  // slot (t-1)&7
        char* spub = ring + (size_t)(g * 8 + (t & 7)) * SLOTB;        // slot t&7
        const bool havew = (t >= 1);
        // early x_proj / z prefetch (8-redundant over q; hides under poll)
        float xp = 0.f, zz = 0.f;
        if (t < 512) {
            size_t m = (size_t)(g * 512 + t) * 2048 + s * 64 + cc;
            xp = (float)xz[m];
            zz = (float)xz[m + 1024];
        }
        f32x2 wv2 = (f32x2){0.f, 0.f};
        if (havew) {
            // ---- the single sync of the step: 16 parallel sentinel lines ----
            if (!dead && lane < 16) {
                int spin = 0;
                while (ldsen(&sen[(size_t)(senb + lane) * 32]) < (u32)t) {
                    if (++spin > 2000000) { dead = true; break; }
                    __builtin_amdgcn_s_sleep(1);
                }
            }
            asm volatile("" ::: "memory");
            // gather full h_{t-1} -> h_prev (read post-B1)
            if (tid < 128) {
                const u64* Hp = (const u64*)(srd + R_H);
                Pk2 u;
                u.u[0] = ldq(&Hp[tid * 2], mall);
                u.u[1] = ldq(&Hp[tid * 2 + 1], mall);
                *(half8*)(&h_prev[tid * 8]) = u.h8;
            }
            // wv all-reduce: own 2 dims from 16 producer slices (f16 packed, 4B each)
            const u32* Wp = (const u32*)(srd + R_WVP);
            #pragma unroll
            for (int sl = 0; sl < 16; sl++) {
                PkW u; u.u = ldw(&Wp[sl * 512 + tid], mall);
                wv2[0] += (float)u.h[0]; wv2[1] += (float)u.h[1];
            }
            // write-score partials (wv . tape entering step t-1)
            {
                float p[16];
                #pragma unroll
                for (int n = 0; n < 16; n++) {
                    f32x2 d = tp[n];
                    p[n] = wv2[0]*d[0] + wv2[1]*d[1];
                }
                #pragma unroll
                for (int n = 0; n < 16; n++) p_l[tid * 17 + n] = p[n];
            }
            __syncthreads();                                   // B1: p_l + h_prev ready
            {
                float scw = 0.f;
                #pragma unroll
                for (int m2 = 0; m2 < 16; m2++) scw += p_l[(c32 + 32 * m2) * 17 + nn];
                #pragma unroll
                for (int d2 = 1; d2 < 32; d2 <<= 1) scw += __shfl_xor(scw, d2, 32);
                if (c32 == 0) sc_l[nn] = scw;
            }
            __syncthreads();                                   // B2: sc_l ready
            {   // write softmax (redundant per thread) + lazy tape update
                float e[16], mxw = -1e30f;
                #pragma unroll
                for (int n = 0; n < 16; n++) { e[n] = sc_l[n] * SCALE; mxw = fmaxf(mxw, e[n]); }
                float smw = 0.f;
                #pragma unroll
                for (int n = 0; n < 16; n++) { e[n] = __expf(e[n] - mxw); smw += e[n]; }
                float invw = 1.f / smw;
                #pragma unroll
                for (int n = 0; n < 16; n++) {
                    float wan = e[n] * invw;
                    f32x2 d = tp[n];
                    d[0] += wan * (wv2[0] - d[0]);
                    d[1] += wan * (wv2[1] - d[1]);
                    tp[n] = d;
                }
            }
        }
        if (t == 512) break;   // finale: tape has write of step 511 applied

        // read-score partials (h_{t-1} . tape entering step t)
        {
            half2_t hh = *(const half2_t*)(&h_prev[tid * 2]);
            float h0 = (float)hh[0], h1 = (float)hh[1];
            float p[16];
            #pragma unroll
            for (int n = 0; n < 16; n++) {
                f32x2 d = tp[n];
                p[n] = h0*d[0] + h1*d[1];
            }
            #pragma unroll
            for (int n = 0; n < 16; n++) p_l[tid * 17 + n] = p[n];
        }
        __syncthreads();                                       // B3
        float sc = 0.f;
        #pragma unroll
        for (int m2 = 0; m2 < 16; m2++) sc += p_l[(c32 + 32 * m2) * 17 + nn];
        #pragma unroll
        for (int d2 = 1; d2 < 32; d2 <<= 1) sc += __shfl_xor(sc, d2, 32);
        if (c32 == 0) sc_l[nn] = sc;
        __syncthreads();                                       // B4
        float r[16], mx = -1e30f;
        #pragma unroll
        for (int n = 0; n < 16; n++) { r[n] = sc_l[n] * SCALE; mx = fmaxf(mx, r[n]); }
        float sm = 0.f;
        #pragma unroll
        for (int n = 0; n < 16; n++) { r[n] = __expf(r[n] - mx); sm += r[n]; }
        float inv = 1.f / sm;
        // read_val, own 2 dims (from register tape)
        f32x2 rv2 = (f32x2){0.f, 0.f};
        #pragma unroll
        for (int n = 0; n < 16; n++) {
            float ra = r[n] * inv;
            rv2[0] += ra * tp[n][0];
            rv2[1] += ra * tp[n][1];
        }
        *(f32x2*)(&rv_l[tid * 2]) = rv2;
        // Wh matvec (col-role): full h_{t-1} from LDS, xor'd chunk order
        float a0 = 0.f, a1 = 0.f, a2 = 0.f, a3 = 0.f;
        #pragma unroll
        for (int jj = 0; jj < 16; jj++) {
            half8 hp8 = *(const half8*)(&h_prev[q * 128 + (((jj ^ qx) & 15) * 8)]);
            half8 wc = whr[jj];
            FDOT(hp2(wc,0), hp2(hp8,0), a0);
            FDOT(hp2(wc,1), hp2(hp8,1), a1);
            FDOT(hp2(wc,2), hp2(hp8,2), a2);
            FDOT(hp2(wc,3), hp2(hp8,3), a3);
        }
        float av = (a0 + a1) + (a2 + a3);
        av += __shfl_xor(av, 1);
        av += __shfl_xor(av, 2);
        av += __shfl_xor(av, 4);
        __syncthreads();                                       // B5: rv_l ready
        float rd = rv_l[s * 64 + cc];
        float hv = tanhf(av + xp + rd + bhc);
        float g2 = zz + rd + hv;
        float o = hv * g2 / (1.f + __expf(-g2));
        if (q == 0) h_own[cc] = (_Float16)hv;
        __syncthreads();                                       // B6: h_own ready
        // wvp partials: rows 2*tid..+1 over own 64 k (h_own broadcast reads)
        half8 hr[8];
        #pragma unroll
        for (int kk = 0; kk < 8; kk++) hr[kk] = *(const half8*)(&h_own[kk * 8]);
        float w0 = 0.f, w1 = 0.f;
        #pragma unroll
        for (int kk = 0; kk < 8; kk++) {
            half8 h8 = hr[kk];
            #pragma unroll
            for (int pp = 0; pp < 4; pp++) {
                FDOT(hp2(wwr[0][kk],pp), hp2(h8,pp), w0);
                FDOT(hp2(wwr[1][kk],pp), hp2(h8,pp), w1);
            }
        }
        {   // publish wvp (packed f16 half2, 4B) + h slice into slot t&7
            PkW wq;
            wq.h = (half2_t){(_Float16)w0, (_Float16)w1};
            stw(&((u32*)(spub + R_WVP))[s * 512 + tid], wq.u, mall);
            if (tid < 8) {
                Pk2 u; u.h8 = *(const half8*)(&h_own[tid * 8]);
                u64* Hp = (u64*)(spub + R_H);
                stq(&Hp[s * 16 + tid * 2],     u.u[0], mall);
                stq(&Hp[s * 16 + tid * 2 + 1], u.u[1], mall);
            }
        }
        __syncthreads();                                       // B7: vmcnt drain (h + wvp)
        if (tid == 0) stsen(senrow, (u32)(t + 1));
        // deferred out store (off the sentinel critical path)
        if (q == 0) out[(size_t)(g * 512 + t) * 1024 + s * 64 + cc] = o;
    }
    // ================= finale: write h_tape_final (slice 0 of each group) =================
    if (s == 0) {
        #pragma unroll
        for (int n = 0; n < 16; n++)
            *(f32x2*)(&out[8388608ULL + (size_t)(g * 16 + n) * 1024 + tid * 2]) = tp[n];
    }
}

extern "C" void kernel_launch(void* const* d_in, const int* in_sizes, int n_in,
                              void* d_out, int out_size, void* d_ws, size_t ws_size,
                              hipStream_t stream) {
    const float* x     = (const float*)d_in[0];
    const float* tape0 = (const float*)d_in[1];
    const float* h0    = (const float*)d_in[2];
    const float* Wh    = (const float*)d_in[3];
    const float* Wxz   = (const float*)d_in[4];
    const float* bh    = (const float*)d_in[5];
    const float* Ww    = (const float*)d_in[6];

    char* ws = (char*)d_ws;
    _Float16* xbf   = (_Float16*)(ws + XBF_OFF);
    _Float16* wxzbf = (_Float16*)(ws + WXZ_OFF);
    _Float16* whbf  = (_Float16*)(ws + WH_OFF);
    _Float16* wwbf  = (_Float16*)(ws + WW_OFF);
    _Float16* xzbf  = (_Float16*)(ws + XZ_OFF);
    char* ring      = ws + RING_OFF;
    u32* vote       = (u32*)(ws + VOTE_OFF);
    u32* sen        = (u32*)(ws + SEN_OFF);

    // vote (4 KB) + sentinels (32 KB): zeroed every launch
    hipMemsetAsync(ws + VOTE_OFF, 0, 4096 + 32768, stream);

    cvt_kernel<<<8192, 256, 0, stream>>>(x, xbf, 2097152);
    cvt_kernel<<<2048, 256, 0, stream>>>(Wxz, wxzbf, 524288);
    cvt_kernel<<<1024, 256, 0, stream>>>(Wh, whbf, 262144);
    cvt_kernel<<<1024, 256, 0, stream>>>(Ww, wwbf, 262144);

    gemm_xz<<<dim3(16, 64), 256, 0, stream>>>(xbf, wxzbf, xzbf);

    scan_kernel<<<256, 512, 0, stream>>>(xzbf, tape0, h0, bh, whbf, wwbf,
                                         ring, sen, vote, (float*)d_out);
}